// Round 3
// baseline (632.554 us; speedup 1.0000x reference)
//
#include <hip/hip_runtime.h>

// ct_layer round 10: 2-wave (128-thread) co-half blocks everywhere.
//   R9 post-mortem: acc[4][8]=128 AGPR + 116 VGPR ~= 244/wave -> hard 2
//   waves/SIMD; with 4-wave blocks that means 2 blocks/CU and a 33% grid-
//   quantization tail (1152 @ 512 concurrent = 2.25 rounds -> 3). W4's 64n
//   waves were L2-weight-BW-bound (52 B/cyc/CU ~= ceiling).
//   Fix: block = 2 waves x (64co x 128n) = 128co x 128n, co-half split:
//     - same proven cb loop (288 MFMA/wave/cb, 26 B/cyc weight traffic)
//     - 4 blocks/CU: p12 grid 2304 -> 1024+1024+256 (tail ~0%)
//                    c1f/c2 grid 1152 -> 1024+128 (tail ~11%)

typedef _Float16 f16x8 __attribute__((ext_vector_type(8)));
typedef _Float16 f16x4v __attribute__((ext_vector_type(4)));
typedef float f32x4 __attribute__((ext_vector_type(4)));

#define HP 98
#define WP 98
#define KTOT 2304
#define WSET (256*KTOT)                // 589824 elems per weight set
#define XPAD_E ((size_t)8*HP*WP*256)
#define UVP_E  ((size_t)8*98*256)      // u_pad/v_pad f32 (atomic targets)
#define UV2_E  ((size_t)3*8*96*256)    // u2/v2 f32 [case][b][pos][co]
#define WUV_SET 196608                 // 256co * 768k per (t,case)

// XCD-aware block swizzle (requires nwg % 8 == 0).
__device__ __forceinline__ int xcd_swz(int bid, int nwg)
{
  return (bid & 7) * (nwg >> 3) + (bid >> 3);
}

// ---------------- 2-wave conv core: 64co x 128n per wave ------------------
#define BUF_B 12288                    // staged ci-slice: 192 pos * 64B
#define SMEM_B 24576

struct CtxH {
  unsigned goff[6];
  unsigned lds_stage;
  unsigned aoff;
  int wl, quad, wv;
  int b, h0, w0;
};

// TR=0: tile 8h x 16w, halo 10x18, lane dim = w, j = h
// TR=1: tile 16h x 8w, halo 18x10, lane dim = h, j = w
template<int TR>
__device__ __forceinline__ CtxH make_ctxH(int spatial, int ch)
{
  CtxH c;
  c.b = spatial / 72;
  const int tt = spatial - c.b * 72;
  if (TR == 0) { const int ht = tt / 6,  wt = tt - ht * 6;  c.h0 = ht * 8;  c.w0 = wt * 16; }
  else         { const int ht = tt / 12, wt = tt - ht * 12; c.h0 = ht * 16; c.w0 = wt * 8;  }
  const int tid = threadIdx.x, lane = tid & 63;
  c.wv = tid >> 6;                               // 0..1
  c.quad = lane >> 4; c.wl = lane & 15;
  c.aoff = (unsigned)((ch * 8 + c.wv * 4) * 512 + c.wl * 32 + c.quad * 8);
  const unsigned base_hw = (unsigned)(c.b * HP + c.h0) * WP + c.w0;
#pragma unroll
  for (int t = 0; t < 6; ++t) {
    int pos = (c.wv * 6 + t) * 16 + (lane >> 2); // 0..191; 180..191 dummy
    if (pos > 179) pos = 179;
    const int wh = (TR == 0) ? pos / 18 : pos / 10;
    const int ww = (TR == 0) ? pos - wh * 18 : pos - wh * 10;
    c.goff[t] = (base_hw + (unsigned)(wh * WP + ww)) * 256u + (lane & 3) * 8u;
  }
  c.lds_stage = (unsigned)(c.wv * 6) * 1024u + (unsigned)lane * 16u;
  return c;
}

__device__ __forceinline__ void stage_cbH(const _Float16* __restrict__ src,
                                          char* sbuf, const CtxH& c, int buf, int cb)
{
  char* l0 = sbuf + buf * BUF_B + c.lds_stage;
#pragma unroll
  for (int t = 0; t < 6; ++t) {
    const _Float16* g = src + c.goff[t] + cb * 32;
    __builtin_amdgcn_global_load_lds(
        (const __attribute__((address_space(1))) void*)g,
        (__attribute__((address_space(3))) void*)(l0 + t * 1024), 16, 0, 0);
  }
}

// Weight tile layout: idx = ((cb*9+tap)*16 + cog)*512 + m*32 + kk.
template<int TR>
__device__ __forceinline__ void conv_accumH(const _Float16* __restrict__ src,
                                            const _Float16* __restrict__ wkb,
                                            char* sbuf, const CtxH& c, f32x4 acc[4][8])
{
  const _Float16* A0 = wkb + c.aoff;
  stage_cbH(src, sbuf, c, 0, 0);
#pragma unroll 1
  for (int cb = 0; cb < 8; ++cb) {
    __syncthreads();
    if (cb < 7) stage_cbH(src, sbuf, c, (cb + 1) & 1, cb + 1);
    const _Float16* B = (const _Float16*)(sbuf + (cb & 1) * BUF_B);
    const _Float16* A = A0 + cb * (9 * 8192);
#pragma unroll
    for (int o = 0; o < 3; ++o) {                  // TR0: o=dw ; TR1: o=dh
      f16x8 cache[10];
#pragma unroll
      for (int r = 0; r < 10; ++r)
        cache[r] = (TR == 0)
            ? *(const f16x8*)(B + (r * 18 + c.wl + o) * 32 + c.quad * 8)
            : *(const f16x8*)(B + ((c.wl + o) * 10 + r) * 32 + c.quad * 8);
#pragma unroll
      for (int p = 0; p < 3; ++p) {                // TR0: p=dh ; TR1: p=dw
        const int tap = (TR == 0) ? p * 3 + o : o * 3 + p;
        f16x8 af[4];
#pragma unroll
        for (int i = 0; i < 4; ++i)
          af[i] = *(const f16x8*)(A + tap * 8192 + i * 512);
#pragma unroll
        for (int i = 0; i < 4; ++i)
#pragma unroll
          for (int j = 0; j < 8; ++j)
            acc[i][j] = __builtin_amdgcn_mfma_f32_16x16x32_f16(af[i], cache[j + p], acc[i][j], 0, 0, 0);
      }
    }
  }
  __syncthreads();
}

#define ZERO_ACC8(acc) \
  _Pragma("unroll") for (int i = 0; i < 4; ++i) \
  _Pragma("unroll") for (int j = 0; j < 8; ++j) acc[i][j] = (f32x4){0.f,0.f,0.f,0.f};

// ---------------- p12: conv -> relu -> axis max -> atomicMax --------------
__global__ __launch_bounds__(128, 2) void k_conv_p12(
    const _Float16* __restrict__ xpad, const _Float16* __restrict__ wk,
    const float* __restrict__ bias1, const float* __restrict__ bias2,
    float* __restrict__ u_pad, float* __restrict__ v_pad)
{
  __shared__ __align__(16) char smem[SMEM_B];
  const int lin = xcd_swz(blockIdx.x, 2304);
  const int set = lin >= 1152;
  const int rem = lin - set * 1152;
  const int spatial = rem >> 1, ch = rem & 1;
  f32x4 acc[4][8];
  ZERO_ACC8(acc)
  if (set == 0) {
    CtxH c = make_ctxH<0>(spatial, ch);
    conv_accumH<0>(xpad, wk, smem, c, acc);
#pragma unroll
    for (int i = 0; i < 4; ++i) {
      const int co = (ch * 8 + c.wv * 4 + i) * 16 + c.quad * 4;
      const float4 bs = *(const float4*)(bias1 + co);
      float m0 = 0.f, m1 = 0.f, m2 = 0.f, m3 = 0.f;
#pragma unroll
      for (int j = 0; j < 8; ++j) {                // j = h: in-lane max over h
        m0 = fmaxf(m0, acc[i][j][0] + bs.x);
        m1 = fmaxf(m1, acc[i][j][1] + bs.y);
        m2 = fmaxf(m2, acc[i][j][2] + bs.z);
        m3 = fmaxf(m3, acc[i][j][3] + bs.w);
      }
      unsigned* tgt = (unsigned*)(u_pad + ((size_t)c.b * 98 + (c.w0 + c.wl + 1)) * 256 + co);
      atomicMax(tgt + 0, __float_as_uint(m0));
      atomicMax(tgt + 1, __float_as_uint(m1));
      atomicMax(tgt + 2, __float_as_uint(m2));
      atomicMax(tgt + 3, __float_as_uint(m3));
    }
  } else {
    CtxH c = make_ctxH<1>(spatial, ch);
    conv_accumH<1>(xpad, wk + WSET, smem, c, acc);
#pragma unroll
    for (int i = 0; i < 4; ++i) {
      const int co = (ch * 8 + c.wv * 4 + i) * 16 + c.quad * 4;
      const float4 bs = *(const float4*)(bias2 + co);
      float m0 = 0.f, m1 = 0.f, m2 = 0.f, m3 = 0.f;
#pragma unroll
      for (int j = 0; j < 8; ++j) {                // j = w: in-lane max over w
        m0 = fmaxf(m0, acc[i][j][0] + bs.x);
        m1 = fmaxf(m1, acc[i][j][1] + bs.y);
        m2 = fmaxf(m2, acc[i][j][2] + bs.z);
        m3 = fmaxf(m3, acc[i][j][3] + bs.w);
      }
      unsigned* tgt = (unsigned*)(v_pad + ((size_t)c.b * 98 + (c.h0 + c.wl + 1)) * 256 + co);
      atomicMax(tgt + 0, __float_as_uint(m0));
      atomicMax(tgt + 1, __float_as_uint(m1));
      atomicMax(tgt + 2, __float_as_uint(m2));
      atomicMax(tgt + 3, __float_as_uint(m3));
    }
  }
}

// ---------------- 1D convs of u,v with case-summed weights ----------------
__global__ __launch_bounds__(256, 2) void k_uv1d(
    const float* __restrict__ u_pad, const float* __restrict__ v_pad,
    const _Float16* __restrict__ wuv, float* __restrict__ u2, float* __restrict__ v2)
{
  const int id = blockIdx.x;
  const int b = id & 7, cs = (id >> 3) % 3, t = id / 24;
  const float* src = t ? v_pad : u_pad;
  float* dst = t ? v2 : u2;
  const _Float16* A0 = wuv + (size_t)(t * 3 + cs) * WUV_SET;
  const int lane = threadIdx.x & 63, wv = threadIdx.x >> 6;
  const int quad = lane >> 4, l16 = lane & 15;

  f32x4 acc[4][6];
#pragma unroll
  for (int i = 0; i < 4; ++i)
#pragma unroll
    for (int j = 0; j < 6; ++j) acc[i][j] = (f32x4){0.f, 0.f, 0.f, 0.f};

#pragma unroll 1
  for (int kb = 0; kb < 24; ++kb) {
    const int dw = kb >> 3, cb = kb & 7;
    f16x8 bf[6];
#pragma unroll
    for (int j = 0; j < 6; ++j) {
      const int pos = j * 16 + l16;
      const float* p = src + ((size_t)b * 98 + (pos + dw)) * 256 + cb * 32 + quad * 8;
      const float4 x0 = *(const float4*)p;
      const float4 x1 = *(const float4*)(p + 4);
      f16x8 v;
      v[0] = (_Float16)x0.x; v[1] = (_Float16)x0.y; v[2] = (_Float16)x0.z; v[3] = (_Float16)x0.w;
      v[4] = (_Float16)x1.x; v[5] = (_Float16)x1.y; v[6] = (_Float16)x1.z; v[7] = (_Float16)x1.w;
      bf[j] = v;
    }
    f16x8 af[4];
#pragma unroll
    for (int i = 0; i < 4; ++i)
      af[i] = *(const f16x8*)(A0 + (size_t)(kb * 16 + wv * 4 + i) * 512 + l16 * 32 + quad * 8);
#pragma unroll
    for (int i = 0; i < 4; ++i)
#pragma unroll
      for (int j = 0; j < 6; ++j)
        acc[i][j] = __builtin_amdgcn_mfma_f32_16x16x32_f16(af[i], bf[j], acc[i][j], 0, 0, 0);
  }
#pragma unroll
  for (int i = 0; i < 4; ++i)
#pragma unroll
    for (int j = 0; j < 6; ++j) {
      const int pos = j * 16 + l16;
      const int co = wv * 64 + i * 16 + quad * 4;
      *(f32x4*)(dst + ((size_t)(cs * 8 + b) * 96 + pos) * 256 + co) = acc[i][j];
    }
}

// ---------------- conv_c1 + U' + V' + biases, relu -> r_pad NHWC f16 ------
__global__ __launch_bounds__(128, 2) void k_conv_c1f(
    const _Float16* __restrict__ xpad, const _Float16* __restrict__ wkc1,
    const float* __restrict__ bias_p, const float* __restrict__ bias_c1,
    const float* __restrict__ u2, const float* __restrict__ v2,
    _Float16* __restrict__ rpad)
{
  __shared__ __align__(16) char smem[SMEM_B];
  const int lin = xcd_swz(blockIdx.x, 1152);
  const int spatial = lin >> 1, ch = lin & 1;
  CtxH c = make_ctxH<0>(spatial, ch);
  f32x4 acc[4][8];
  ZERO_ACC8(acc)
  conv_accumH<0>(xpad, wkc1, smem, c, acc);

  const int w = c.w0 + c.wl;
  const int wcase = (w == 0) ? 0 : ((w == 95) ? 2 : 1);
#pragma unroll
  for (int i = 0; i < 4; ++i) {
    const int co = (ch * 8 + c.wv * 4 + i) * 16 + c.quad * 4;
    float4 bs = *(const float4*)(bias_p + co);
    const float4 b2 = *(const float4*)(bias_c1 + co);
    bs.x += b2.x; bs.y += b2.y; bs.z += b2.z; bs.w += b2.w;
#pragma unroll
    for (int j = 0; j < 8; ++j) {
      const int h = c.h0 + j;
      const int hcase = (h == 0) ? 0 : ((h == 95) ? 2 : 1);
      const float4 uq = *(const float4*)(u2 + ((size_t)(hcase * 8 + c.b) * 96 + w) * 256 + co);
      const float4 vq = *(const float4*)(v2 + ((size_t)(wcase * 8 + c.b) * 96 + h) * 256 + co);
      f16x4v pk;
      pk[0] = (_Float16)fmaxf(acc[i][j][0] + bs.x + uq.x + vq.x, 0.f);
      pk[1] = (_Float16)fmaxf(acc[i][j][1] + bs.y + uq.y + vq.y, 0.f);
      pk[2] = (_Float16)fmaxf(acc[i][j][2] + bs.z + uq.z + vq.z, 0.f);
      pk[3] = (_Float16)fmaxf(acc[i][j][3] + bs.w + uq.w + vq.w, 0.f);
      *(f16x4v*)(rpad + ((size_t)(c.b * HP + h + 1) * WP + w + 1) * 256 + co) = pk;
    }
  }
}

// ---------------- final conv, relu, NCHW f32 to d_out ---------------------
__global__ __launch_bounds__(128, 2) void k_conv_c2(
    const _Float16* __restrict__ rpad, const _Float16* __restrict__ wkc2,
    const float* __restrict__ bias, float* __restrict__ dout)
{
  __shared__ __align__(16) char smem[SMEM_B];
  const int lin = xcd_swz(blockIdx.x, 1152);
  const int spatial = lin >> 1, ch = lin & 1;
  CtxH c = make_ctxH<0>(spatial, ch);
  f32x4 acc[4][8];
  ZERO_ACC8(acc)
  conv_accumH<0>(rpad, wkc2, smem, c, acc);

  const int w = c.w0 + c.wl;
#pragma unroll
  for (int j = 0; j < 8; ++j) {
    const int h = c.h0 + j;
    float* op = dout + (size_t)c.b * 2359296 + h * 96 + w;
#pragma unroll
    for (int i = 0; i < 4; ++i) {
      const int co = (ch * 8 + c.wv * 4 + i) * 16 + c.quad * 4;
      const float4 bs = *(const float4*)(bias + co);
      op[(size_t)(co + 0) * 9216] = fmaxf(acc[i][j][0] + bs.x, 0.f);
      op[(size_t)(co + 1) * 9216] = fmaxf(acc[i][j][1] + bs.y, 0.f);
      op[(size_t)(co + 2) * 9216] = fmaxf(acc[i][j][2] + bs.z, 0.f);
      op[(size_t)(co + 3) * 9216] = fmaxf(acc[i][j][3] + bs.w, 0.f);
    }
  }
}

// ---------------- aux kernels ---------------------------------------------
// Zero the 1-px halo ring of x_pad (z=0) and r_pad (z=1). 388 border pos/img.
__global__ void k_border(_Float16* __restrict__ xpad, _Float16* __restrict__ rpad)
{
  const int idx = blockIdx.x, b = blockIdx.y;
  _Float16* buf = blockIdx.z ? rpad : xpad;
  int h, w;
  if (idx < 98)       { h = 0;  w = idx; }
  else if (idx < 196) { h = 97; w = idx - 98; }
  else { const int r = idx - 196; h = 1 + (r >> 1); w = (r & 1) ? 97 : 0; }
  buf[((size_t)(b * HP + h) * WP + w) * 256 + threadIdx.x] = (_Float16)0.f;
}

__global__ void k_pack_x(const float* __restrict__ x, _Float16* __restrict__ xpad)
{
  __shared__ float tile[32][33];
  const int bh = blockIdx.x;
  const int b = bh / 96, h = bh - b * 96;
  const int c0 = blockIdx.y * 32, w0 = blockIdx.z * 32;
  const int tx = threadIdx.x & 31, ty = threadIdx.x >> 5;
#pragma unroll
  for (int i = 0; i < 4; ++i) {
    int cI = c0 + ty + i * 8;
    tile[ty + i * 8][tx] = x[(((size_t)b * 256 + cI) * 96 + h) * 96 + w0 + tx];
  }
  __syncthreads();
#pragma unroll
  for (int i = 0; i < 4; ++i) {
    int w = w0 + ty + i * 8;
    xpad[((size_t)(b * HP + h + 1) * WP + (w + 1)) * 256 + c0 + tx] =
        (_Float16)tile[tx][ty + i * 8];
  }
}

// main conv weights -> tiled layout: idx = ((cb*9+tap)*16 + cog)*512 + m*32 + kk
__global__ void k_repack_w(const float* w0, const float* g0, const float* w1, const float* g1,
                           const float* w2, const float* g2, const float* w3, const float* g3,
                           const float* w4, const float* g4, _Float16* __restrict__ wk)
{
  const int set = blockIdx.y;
  const float* w; const float* g;
  switch (set) {
    case 0: w = w0; g = g0; break;
    case 1: w = w1; g = g1; break;
    case 2: w = w2; g = g2; break;
    case 3: w = w3; g = g3; break;
    default: w = w4; g = g4; break;
  }
  const int t = blockIdx.x * 256 + threadIdx.x;   // co*256 + ci
  const int co = t >> 8, ci = t & 255;
  const int cb = ci >> 5, kk = ci & 31, cog = co >> 4, m = co & 15;
  const float gv = g[co];
  const float* src = w + ((size_t)co * 256 + ci) * 9;
  _Float16* dst = wk + (size_t)set * WSET + cog * 512 + m * 32 + kk;
#pragma unroll
  for (int tap = 0; tap < 9; ++tap)
    dst[(cb * 9 + tap) * 8192] = (_Float16)(src[tap] * gv);
}

// case-summed 1D weights for U'/V'
__global__ void k_repack_uvw(const float* __restrict__ wp, const float* __restrict__ gp,
                             _Float16* __restrict__ wuv)
{
  const int tcs = blockIdx.y;                             // 0..5 = t*3+cs
  const int tt = tcs / 3, cs = tcs - tt * 3;
  const int idx = blockIdx.x * 256 + threadIdx.x;         // co*256 + ci
  const int co = idx >> 8, ci = idx & 255;
  const float gv = gp[co];
  const float* src = wp + ((size_t)co * 256 + ci) * 9;    // [dh][dw]
  const int lo = (cs == 0) ? 1 : 0, hi = (cs == 2) ? 1 : 2;
  _Float16* base = wuv + (size_t)tcs * WUV_SET;
#pragma unroll
  for (int d = 0; d < 3; ++d) {
    float s = 0.f;
    for (int e = lo; e <= hi; ++e)
      s += (tt == 0) ? src[e * 3 + d] : src[d * 3 + e];
    const int k = d * 256 + ci;
    const int kb = k >> 5, kk = k & 31;
    base[(size_t)(kb * 16 + (co >> 4)) * 512 + (co & 15) * 32 + kk] = (_Float16)(s * gv);
  }
}

// ---------------- launcher -------------------------------------------------
extern "C" void kernel_launch(void* const* d_in, const int* in_sizes, int n_in,
                              void* d_out, int out_size, void* d_ws, size_t ws_size,
                              hipStream_t stream)
{
  const float* x    = (const float*)d_in[0];
  const float* w_p1 = (const float*)d_in[1];
  const float* g_p1 = (const float*)d_in[2];
  const float* b_p1 = (const float*)d_in[3];
  const float* w_p2 = (const float*)d_in[4];
  const float* g_p2 = (const float*)d_in[5];
  const float* b_p2 = (const float*)d_in[6];
  const float* w_p  = (const float*)d_in[7];
  const float* g_p  = (const float*)d_in[8];
  const float* b_p  = (const float*)d_in[9];
  const float* w_c1 = (const float*)d_in[10];
  const float* g_c1 = (const float*)d_in[11];
  const float* b_c1 = (const float*)d_in[12];
  const float* w_c2 = (const float*)d_in[13];
  const float* g_c2 = (const float*)d_in[14];
  const float* b_c2 = (const float*)d_in[15];

  char* ws = (char*)d_ws;
  size_t off = 0;
  _Float16* x_pad = (_Float16*)(ws + off); off += XPAD_E * 2;
  _Float16* r_pad = (_Float16*)(ws + off); off += XPAD_E * 2;
  _Float16* wks   = (_Float16*)(ws + off); off += (size_t)5 * WSET * 2;
  _Float16* wuv   = (_Float16*)(ws + off); off += (size_t)6 * WUV_SET * 2;
  float*    u_pad = (float*)(ws + off);    off += UVP_E * 4;
  float*    v_pad = (float*)(ws + off);    off += UVP_E * 4;
  float*    u2    = (float*)(ws + off);    off += UV2_E * 4;
  float*    v2    = (float*)(ws + off);    off += UV2_E * 4;
  (void)ws_size; (void)in_sizes; (void)n_in; (void)out_size;

  hipMemsetAsync(u_pad, 0, UVP_E * 4, stream);     // atomicMax targets + zero pad
  hipMemsetAsync(v_pad, 0, UVP_E * 4, stream);

  k_border    <<<dim3(388, 8, 2), 256, 0, stream>>>(x_pad, r_pad);
  k_pack_x    <<<dim3(768, 8, 3), 256, 0, stream>>>(x, x_pad);
  k_repack_w  <<<dim3(256, 5),    256, 0, stream>>>(w_p1, g_p1, w_p2, g_p2, w_p, g_p,
                                                    w_c1, g_c1, w_c2, g_c2, wks);
  k_repack_uvw<<<dim3(256, 6),    256, 0, stream>>>(w_p, g_p, wuv);
  k_conv_p12  <<<2304, 128, 0, stream>>>(x_pad, wks, b_p1, b_p2, u_pad, v_pad);
  k_uv1d      <<<48,   256, 0, stream>>>(u_pad, v_pad, wuv, u2, v2);
  k_conv_c1f  <<<1152, 128, 0, stream>>>(x_pad, wks + (size_t)3 * WSET, b_p, b_c1,
                                         u2, v2, r_pad);
  k_conv_c2   <<<1152, 128, 0, stream>>>(r_pad, wks + (size_t)4 * WSET, b_c2,
                                         (float*)d_out);
}

// Round 4
// 560.568 us; speedup vs baseline: 1.1284x; 1.1284x over previous
//
#include <hip/hip_runtime.h>

// ct_layer round 11: Q16 core for p12; c1f/c2 reverted to R9's W4 (measured best).
//   Analysis: weight L2 demand at full MFMA pipe = 844/j B/cyc vs 56 B/cyc
//   ceiling -> j=8 cores cap at 53% MfmaUtil (measured 40). Q16: waves of
//   32co x 256n (acc[2][16], j=16) halve weight traffic -> demand 52.7 B/cyc.
//   Also: TR1 ds_read bank imbalance (stride-10 rows) fixed by storing the
//   set-1 halo w-major -> both sets read the contiguous conflict-free pattern.

typedef _Float16 f16x8 __attribute__((ext_vector_type(8)));
typedef _Float16 f16x4v __attribute__((ext_vector_type(4)));
typedef float f32x4 __attribute__((ext_vector_type(4)));

#define HP 98
#define WP 98
#define KTOT 2304
#define WSET (256*KTOT)                // 589824 elems per weight set
#define XPAD_E ((size_t)8*HP*WP*256)
#define UVP_E  ((size_t)8*98*256)      // u_pad/v_pad f32 (atomic targets)
#define UV2_E  ((size_t)3*8*96*256)    // u2/v2 f32 [case][b][pos][co]
#define WUV_SET 196608                 // 256co * 768k per (t,case)

// XCD-aware block swizzle (requires nwg % 8 == 0).
__device__ __forceinline__ int xcd_swz(int bid, int nwg)
{
  return (bid & 7) * (nwg >> 3) + (bid >> 3);
}

// ---------------- Q16 conv core (p12): 32co x 256n per wave ---------------
// Block = 4 waves x (2 cogs each) = 128 co x 256 n (16h x 16w tile).
// Halo 18x18 = 324 pos staged as 384 slots (24 KB), double-buffered.
// SW=0: halo h-major (set0: lane=w, j=h); SW=1: w-major (set1: lane=h, j=w).
// Both read: cache[r] = B[(r*18 + wl + o)*32 + quad*8]  (contiguous 1KB/instr).
#define BUF_Q 24576
#define SMEM_Q 49152

struct CtxQ {
  unsigned goff[6];
  unsigned lds_stage;
  unsigned aoff;
  int wl, quad, wv;
  int b, h0, w0;
};

template<int SW>
__device__ __forceinline__ CtxQ make_ctxQ(int spatial, int ch)
{
  CtxQ c;
  c.b = spatial / 36;
  const int tt = spatial - c.b * 36;
  const int ht = tt / 6, wt = tt - ht * 6;
  c.h0 = ht * 16; c.w0 = wt * 16;
  const int tid = threadIdx.x, lane = tid & 63;
  c.wv = tid >> 6;
  c.quad = lane >> 4; c.wl = lane & 15;
  c.aoff = (unsigned)((ch * 8 + c.wv * 2) * 512 + c.wl * 32 + c.quad * 8);
  const unsigned base_hw = (unsigned)(c.b * HP + c.h0) * WP + c.w0;
#pragma unroll
  for (int t = 0; t < 6; ++t) {
    int s = (c.wv * 6 + t) * 16 + (lane >> 2);   // 0..383; 324..383 dummy
    if (s > 323) s = 323;
    const int x = s / 18, y = s - x * 18;
    const int wh = SW ? y : x, ww = SW ? x : y;
    c.goff[t] = (base_hw + (unsigned)(wh * WP + ww)) * 256u + (lane & 3) * 8u;
  }
  c.lds_stage = (unsigned)(c.wv * 6) * 1024u + (unsigned)lane * 16u;
  return c;
}

__device__ __forceinline__ void stage_cbQ(const _Float16* __restrict__ src,
                                          char* sbuf, const CtxQ& c, int buf, int cb)
{
  char* l0 = sbuf + buf * BUF_Q + c.lds_stage;
#pragma unroll
  for (int t = 0; t < 6; ++t) {
    const _Float16* g = src + c.goff[t] + cb * 32;
    __builtin_amdgcn_global_load_lds(
        (const __attribute__((address_space(1))) void*)g,
        (__attribute__((address_space(3))) void*)(l0 + t * 1024), 16, 0, 0);
  }
}

// TR: tap = (TR==0) ? p*3+o : o*3+p  (weight layout tap = dh*3+dw).
template<int TR>
__device__ __forceinline__ void conv_accumQ(const _Float16* __restrict__ src,
                                            const _Float16* __restrict__ wkb,
                                            char* sbuf, const CtxQ& c, f32x4 acc[2][16])
{
  const _Float16* A0 = wkb + c.aoff;
  stage_cbQ(src, sbuf, c, 0, 0);
#pragma unroll 1
  for (int cb = 0; cb < 8; ++cb) {
    __syncthreads();
    if (cb < 7) stage_cbQ(src, sbuf, c, (cb + 1) & 1, cb + 1);
    const _Float16* B = (const _Float16*)(sbuf + (cb & 1) * BUF_Q);
    const _Float16* A = A0 + cb * (9 * 8192);
#pragma unroll
    for (int o = 0; o < 3; ++o) {
      f16x8 af[3][2];                              // hoisted across both jh halves
#pragma unroll
      for (int p = 0; p < 3; ++p) {
        const int tap = (TR == 0) ? p * 3 + o : o * 3 + p;
#pragma unroll
        for (int i = 0; i < 2; ++i)
          af[p][i] = *(const f16x8*)(A + tap * 8192 + i * 512);
      }
#pragma unroll
      for (int jh = 0; jh < 2; ++jh) {
        f16x8 cache[10];
#pragma unroll
        for (int r = 0; r < 10; ++r)
          cache[r] = *(const f16x8*)(B + ((jh * 8 + r) * 18 + c.wl + o) * 32 + c.quad * 8);
#pragma unroll
        for (int p = 0; p < 3; ++p)
#pragma unroll
          for (int i = 0; i < 2; ++i)
#pragma unroll
            for (int j = 0; j < 8; ++j)
              acc[i][jh * 8 + j] = __builtin_amdgcn_mfma_f32_16x16x32_f16(
                  af[p][i], cache[j + p], acc[i][jh * 8 + j], 0, 0, 0);
      }
    }
  }
  __syncthreads();
}

// ---------------- W4 conv core (c1f/c2): 256co x 64n per block ------------
#define BUF_W 7168
#define SMEM_W 14336

struct Ctx4 {
  unsigned goff[2];
  unsigned lds_stage;
  unsigned aoff;
  int nrow;
  int wl, quad, wv;
  int b, h0, w0;
};

__device__ __forceinline__ Ctx4 make_ctx4(int spatial)
{
  Ctx4 c;
  c.b = spatial / 144;
  const int tt = spatial - c.b * 144;
  const int ht = tt / 6,  wt = tt - ht * 6;  c.h0 = ht * 4;  c.w0 = wt * 16;
  const int tid = threadIdx.x, lane = tid & 63;
  c.wv = tid >> 6;
  c.quad = lane >> 4; c.wl = lane & 15;
  c.aoff = (unsigned)(c.wv * 4 * 512 + c.wl * 32 + c.quad * 8);
  const unsigned base_hw = (unsigned)(c.b * HP + c.h0) * WP + c.w0;
  const int r0 = c.wv * 2;                         // waves 0-2: 2 rows; wave 3: 1
  c.nrow = (c.wv < 3) ? 2 : 1;
#pragma unroll
  for (int t = 0; t < 2; ++t) {
    int row = r0 + t; if (row > 6) row = 6;
    int pos = row * 16 + (lane >> 2);              // 0..111; 108..111 dummy
    if (pos > 107) pos = 107;
    const int wh = pos / 18, ww = pos - wh * 18;
    c.goff[t] = (base_hw + (unsigned)(wh * WP + ww)) * 256u + (lane & 3) * 8u;
  }
  c.lds_stage = (unsigned)r0 * 1024u + (unsigned)lane * 16u;
  return c;
}

__device__ __forceinline__ void stage_cb4(const _Float16* __restrict__ src,
                                          char* sbuf, const Ctx4& c, int buf, int cb)
{
  char* l0 = sbuf + buf * BUF_W + c.lds_stage;
#pragma unroll
  for (int t = 0; t < 2; ++t) {
    if (t < c.nrow) {
      const _Float16* g = src + c.goff[t] + cb * 32;
      __builtin_amdgcn_global_load_lds(
          (const __attribute__((address_space(1))) void*)g,
          (__attribute__((address_space(3))) void*)(l0 + t * 1024), 16, 0, 0);
    }
  }
}

__device__ __forceinline__ void conv_accum4(const _Float16* __restrict__ src,
                                            const _Float16* __restrict__ wkb,
                                            char* sbuf, const Ctx4& c, f32x4 acc[4][4])
{
  const _Float16* A0 = wkb + c.aoff;
  stage_cb4(src, sbuf, c, 0, 0);
#pragma unroll 1
  for (int cb = 0; cb < 8; ++cb) {
    __syncthreads();
    if (cb < 7) stage_cb4(src, sbuf, c, (cb + 1) & 1, cb + 1);
    const _Float16* B = (const _Float16*)(sbuf + (cb & 1) * BUF_W);
    const _Float16* A = A0 + cb * (9 * 8192);
#pragma unroll
    for (int o = 0; o < 3; ++o) {
      f16x8 cache[6];
#pragma unroll
      for (int r = 0; r < 6; ++r)
        cache[r] = *(const f16x8*)(B + (r * 18 + c.wl + o) * 32 + c.quad * 8);
#pragma unroll
      for (int p = 0; p < 3; ++p) {
        const int tap = p * 3 + o;
        f16x8 af[4];
#pragma unroll
        for (int i = 0; i < 4; ++i)
          af[i] = *(const f16x8*)(A + tap * 8192 + i * 512);
#pragma unroll
        for (int i = 0; i < 4; ++i)
#pragma unroll
          for (int j = 0; j < 4; ++j)
            acc[i][j] = __builtin_amdgcn_mfma_f32_16x16x32_f16(af[i], cache[j + p], acc[i][j], 0, 0, 0);
      }
    }
  }
  __syncthreads();
}

// ---------------- p12: conv -> relu -> axis max -> atomicMax --------------
__global__ __launch_bounds__(256, 2) void k_conv_p12(
    const _Float16* __restrict__ xpad, const _Float16* __restrict__ wk,
    const float* __restrict__ bias1, const float* __restrict__ bias2,
    float* __restrict__ u_pad, float* __restrict__ v_pad)
{
  __shared__ __align__(16) char smem[SMEM_Q];
  const int lin = xcd_swz(blockIdx.x, 1152);
  const int set = lin >= 576;
  const int rem = lin - set * 576;
  const int spatial = rem >> 1, ch = rem & 1;
  f32x4 acc[2][16];
#pragma unroll
  for (int i = 0; i < 2; ++i)
#pragma unroll
    for (int j = 0; j < 16; ++j) acc[i][j] = (f32x4){0.f, 0.f, 0.f, 0.f};
  if (set == 0) {
    CtxQ c = make_ctxQ<0>(spatial, ch);
    conv_accumQ<0>(xpad, wk, smem, c, acc);
#pragma unroll
    for (int i = 0; i < 2; ++i) {
      const int co = (ch * 8 + c.wv * 2 + i) * 16 + c.quad * 4;
      const float4 bs = *(const float4*)(bias1 + co);
      float m0 = 0.f, m1 = 0.f, m2 = 0.f, m3 = 0.f;
#pragma unroll
      for (int j = 0; j < 16; ++j) {               // j = h: in-lane max over h
        m0 = fmaxf(m0, acc[i][j][0] + bs.x);
        m1 = fmaxf(m1, acc[i][j][1] + bs.y);
        m2 = fmaxf(m2, acc[i][j][2] + bs.z);
        m3 = fmaxf(m3, acc[i][j][3] + bs.w);
      }
      unsigned* tgt = (unsigned*)(u_pad + ((size_t)c.b * 98 + (c.w0 + c.wl + 1)) * 256 + co);
      atomicMax(tgt + 0, __float_as_uint(m0));
      atomicMax(tgt + 1, __float_as_uint(m1));
      atomicMax(tgt + 2, __float_as_uint(m2));
      atomicMax(tgt + 3, __float_as_uint(m3));
    }
  } else {
    CtxQ c = make_ctxQ<1>(spatial, ch);
    conv_accumQ<1>(xpad, wk + WSET, smem, c, acc);
#pragma unroll
    for (int i = 0; i < 2; ++i) {
      const int co = (ch * 8 + c.wv * 2 + i) * 16 + c.quad * 4;
      const float4 bs = *(const float4*)(bias2 + co);
      float m0 = 0.f, m1 = 0.f, m2 = 0.f, m3 = 0.f;
#pragma unroll
      for (int j = 0; j < 16; ++j) {               // j = w: in-lane max over w
        m0 = fmaxf(m0, acc[i][j][0] + bs.x);
        m1 = fmaxf(m1, acc[i][j][1] + bs.y);
        m2 = fmaxf(m2, acc[i][j][2] + bs.z);
        m3 = fmaxf(m3, acc[i][j][3] + bs.w);
      }
      unsigned* tgt = (unsigned*)(v_pad + ((size_t)c.b * 98 + (c.h0 + c.wl + 1)) * 256 + co);
      atomicMax(tgt + 0, __float_as_uint(m0));
      atomicMax(tgt + 1, __float_as_uint(m1));
      atomicMax(tgt + 2, __float_as_uint(m2));
      atomicMax(tgt + 3, __float_as_uint(m3));
    }
  }
}

// ---------------- 1D convs of u,v with case-summed weights ----------------
__global__ __launch_bounds__(256, 2) void k_uv1d(
    const float* __restrict__ u_pad, const float* __restrict__ v_pad,
    const _Float16* __restrict__ wuv, float* __restrict__ u2, float* __restrict__ v2)
{
  const int id = blockIdx.x;
  const int b = id & 7, cs = (id >> 3) % 3, t = id / 24;
  const float* src = t ? v_pad : u_pad;
  float* dst = t ? v2 : u2;
  const _Float16* A0 = wuv + (size_t)(t * 3 + cs) * WUV_SET;
  const int lane = threadIdx.x & 63, wv = threadIdx.x >> 6;
  const int quad = lane >> 4, l16 = lane & 15;

  f32x4 acc[4][6];
#pragma unroll
  for (int i = 0; i < 4; ++i)
#pragma unroll
    for (int j = 0; j < 6; ++j) acc[i][j] = (f32x4){0.f, 0.f, 0.f, 0.f};

#pragma unroll 1
  for (int kb = 0; kb < 24; ++kb) {
    const int dw = kb >> 3, cb = kb & 7;
    f16x8 bf[6];
#pragma unroll
    for (int j = 0; j < 6; ++j) {
      const int pos = j * 16 + l16;
      const float* p = src + ((size_t)b * 98 + (pos + dw)) * 256 + cb * 32 + quad * 8;
      const float4 x0 = *(const float4*)p;
      const float4 x1 = *(const float4*)(p + 4);
      f16x8 v;
      v[0] = (_Float16)x0.x; v[1] = (_Float16)x0.y; v[2] = (_Float16)x0.z; v[3] = (_Float16)x0.w;
      v[4] = (_Float16)x1.x; v[5] = (_Float16)x1.y; v[6] = (_Float16)x1.z; v[7] = (_Float16)x1.w;
      bf[j] = v;
    }
    f16x8 af[4];
#pragma unroll
    for (int i = 0; i < 4; ++i)
      af[i] = *(const f16x8*)(A0 + (size_t)(kb * 16 + wv * 4 + i) * 512 + l16 * 32 + quad * 8);
#pragma unroll
    for (int i = 0; i < 4; ++i)
#pragma unroll
      for (int j = 0; j < 6; ++j)
        acc[i][j] = __builtin_amdgcn_mfma_f32_16x16x32_f16(af[i], bf[j], acc[i][j], 0, 0, 0);
  }
#pragma unroll
  for (int i = 0; i < 4; ++i)
#pragma unroll
    for (int j = 0; j < 6; ++j) {
      const int pos = j * 16 + l16;
      const int co = wv * 64 + i * 16 + quad * 4;
      *(f32x4*)(dst + ((size_t)(cs * 8 + b) * 96 + pos) * 256 + co) = acc[i][j];
    }
}

// ---------------- conv_c1 + U' + V' + biases, relu -> r_pad NHWC f16 ------
__global__ __launch_bounds__(256, 3) void k_conv_c1f(
    const _Float16* __restrict__ xpad, const _Float16* __restrict__ wkc1,
    const float* __restrict__ bias_p, const float* __restrict__ bias_c1,
    const float* __restrict__ u2, const float* __restrict__ v2,
    _Float16* __restrict__ rpad)
{
  __shared__ __align__(16) char smem[SMEM_W];
  const int lin = xcd_swz(blockIdx.x, 1152);
  Ctx4 c = make_ctx4(lin);
  f32x4 acc[4][4];
#pragma unroll
  for (int i = 0; i < 4; ++i)
#pragma unroll
    for (int j = 0; j < 4; ++j) acc[i][j] = (f32x4){0.f, 0.f, 0.f, 0.f};
  conv_accum4(xpad, wkc1, smem, c, acc);

  const int w = c.w0 + c.wl;
  const int wcase = (w == 0) ? 0 : ((w == 95) ? 2 : 1);
#pragma unroll
  for (int i = 0; i < 4; ++i) {
    const int co = c.wv * 64 + i * 16 + c.quad * 4;
    float4 bs = *(const float4*)(bias_p + co);
    const float4 b2 = *(const float4*)(bias_c1 + co);
    bs.x += b2.x; bs.y += b2.y; bs.z += b2.z; bs.w += b2.w;
#pragma unroll
    for (int j = 0; j < 4; ++j) {
      const int h = c.h0 + j;
      const int hcase = (h == 0) ? 0 : ((h == 95) ? 2 : 1);
      const float4 uq = *(const float4*)(u2 + ((size_t)(hcase * 8 + c.b) * 96 + w) * 256 + co);
      const float4 vq = *(const float4*)(v2 + ((size_t)(wcase * 8 + c.b) * 96 + h) * 256 + co);
      f16x4v pk;
      pk[0] = (_Float16)fmaxf(acc[i][j][0] + bs.x + uq.x + vq.x, 0.f);
      pk[1] = (_Float16)fmaxf(acc[i][j][1] + bs.y + uq.y + vq.y, 0.f);
      pk[2] = (_Float16)fmaxf(acc[i][j][2] + bs.z + uq.z + vq.z, 0.f);
      pk[3] = (_Float16)fmaxf(acc[i][j][3] + bs.w + uq.w + vq.w, 0.f);
      *(f16x4v*)(rpad + ((size_t)(c.b * HP + h + 1) * WP + w + 1) * 256 + co) = pk;
    }
  }
}

// ---------------- final conv, relu, NCHW f32 to d_out ---------------------
__global__ __launch_bounds__(256, 3) void k_conv_c2(
    const _Float16* __restrict__ rpad, const _Float16* __restrict__ wkc2,
    const float* __restrict__ bias, float* __restrict__ dout)
{
  __shared__ __align__(16) char smem[SMEM_W];
  const int lin = xcd_swz(blockIdx.x, 1152);
  Ctx4 c = make_ctx4(lin);
  f32x4 acc[4][4];
#pragma unroll
  for (int i = 0; i < 4; ++i)
#pragma unroll
    for (int j = 0; j < 4; ++j) acc[i][j] = (f32x4){0.f, 0.f, 0.f, 0.f};
  conv_accum4(rpad, wkc2, smem, c, acc);

  const int w = c.w0 + c.wl;
#pragma unroll
  for (int j = 0; j < 4; ++j) {
    const int h = c.h0 + j;
    float* op = dout + (size_t)c.b * 2359296 + h * 96 + w;
#pragma unroll
    for (int i = 0; i < 4; ++i) {
      const int co = c.wv * 64 + i * 16 + c.quad * 4;
      const float4 bs = *(const float4*)(bias + co);
      op[(size_t)(co + 0) * 9216] = fmaxf(acc[i][j][0] + bs.x, 0.f);
      op[(size_t)(co + 1) * 9216] = fmaxf(acc[i][j][1] + bs.y, 0.f);
      op[(size_t)(co + 2) * 9216] = fmaxf(acc[i][j][2] + bs.z, 0.f);
      op[(size_t)(co + 3) * 9216] = fmaxf(acc[i][j][3] + bs.w, 0.f);
    }
  }
}

// ---------------- aux kernels ---------------------------------------------
// Zero the 1-px halo ring of x_pad (z=0) and r_pad (z=1). 388 border pos/img.
__global__ void k_border(_Float16* __restrict__ xpad, _Float16* __restrict__ rpad)
{
  const int idx = blockIdx.x, b = blockIdx.y;
  _Float16* buf = blockIdx.z ? rpad : xpad;
  int h, w;
  if (idx < 98)       { h = 0;  w = idx; }
  else if (idx < 196) { h = 97; w = idx - 98; }
  else { const int r = idx - 196; h = 1 + (r >> 1); w = (r & 1) ? 97 : 0; }
  buf[((size_t)(b * HP + h) * WP + w) * 256 + threadIdx.x] = (_Float16)0.f;
}

__global__ void k_pack_x(const float* __restrict__ x, _Float16* __restrict__ xpad)
{
  __shared__ float tile[32][33];
  const int bh = blockIdx.x;
  const int b = bh / 96, h = bh - b * 96;
  const int c0 = blockIdx.y * 32, w0 = blockIdx.z * 32;
  const int tx = threadIdx.x & 31, ty = threadIdx.x >> 5;
#pragma unroll
  for (int i = 0; i < 4; ++i) {
    int cI = c0 + ty + i * 8;
    tile[ty + i * 8][tx] = x[(((size_t)b * 256 + cI) * 96 + h) * 96 + w0 + tx];
  }
  __syncthreads();
#pragma unroll
  for (int i = 0; i < 4; ++i) {
    int w = w0 + ty + i * 8;
    xpad[((size_t)(b * HP + h + 1) * WP + (w + 1)) * 256 + c0 + tx] =
        (_Float16)tile[tx][ty + i * 8];
  }
}

// main conv weights -> tiled layout: idx = ((cb*9+tap)*16 + cog)*512 + m*32 + kk
__global__ void k_repack_w(const float* w0, const float* g0, const float* w1, const float* g1,
                           const float* w2, const float* g2, const float* w3, const float* g3,
                           const float* w4, const float* g4, _Float16* __restrict__ wk)
{
  const int set = blockIdx.y;
  const float* w; const float* g;
  switch (set) {
    case 0: w = w0; g = g0; break;
    case 1: w = w1; g = g1; break;
    case 2: w = w2; g = g2; break;
    case 3: w = w3; g = g3; break;
    default: w = w4; g = g4; break;
  }
  const int t = blockIdx.x * 256 + threadIdx.x;   // co*256 + ci
  const int co = t >> 8, ci = t & 255;
  const int cb = ci >> 5, kk = ci & 31, cog = co >> 4, m = co & 15;
  const float gv = g[co];
  const float* src = w + ((size_t)co * 256 + ci) * 9;
  _Float16* dst = wk + (size_t)set * WSET + cog * 512 + m * 32 + kk;
#pragma unroll
  for (int tap = 0; tap < 9; ++tap)
    dst[(cb * 9 + tap) * 8192] = (_Float16)(src[tap] * gv);
}

// case-summed 1D weights for U'/V'
__global__ void k_repack_uvw(const float* __restrict__ wp, const float* __restrict__ gp,
                             _Float16* __restrict__ wuv)
{
  const int tcs = blockIdx.y;                             // 0..5 = t*3+cs
  const int tt = tcs / 3, cs = tcs - tt * 3;
  const int idx = blockIdx.x * 256 + threadIdx.x;         // co*256 + ci
  const int co = idx >> 8, ci = idx & 255;
  const float gv = gp[co];
  const float* src = wp + ((size_t)co * 256 + ci) * 9;    // [dh][dw]
  const int lo = (cs == 0) ? 1 : 0, hi = (cs == 2) ? 1 : 2;
  _Float16* base = wuv + (size_t)tcs * WUV_SET;
#pragma unroll
  for (int d = 0; d < 3; ++d) {
    float s = 0.f;
    for (int e = lo; e <= hi; ++e)
      s += (tt == 0) ? src[e * 3 + d] : src[d * 3 + e];
    const int k = d * 256 + ci;
    const int kb = k >> 5, kk = k & 31;
    base[(size_t)(kb * 16 + (co >> 4)) * 512 + (co & 15) * 32 + kk] = (_Float16)(s * gv);
  }
}

// ---------------- launcher -------------------------------------------------
extern "C" void kernel_launch(void* const* d_in, const int* in_sizes, int n_in,
                              void* d_out, int out_size, void* d_ws, size_t ws_size,
                              hipStream_t stream)
{
  const float* x    = (const float*)d_in[0];
  const float* w_p1 = (const float*)d_in[1];
  const float* g_p1 = (const float*)d_in[2];
  const float* b_p1 = (const float*)d_in[3];
  const float* w_p2 = (const float*)d_in[4];
  const float* g_p2 = (const float*)d_in[5];
  const float* b_p2 = (const float*)d_in[6];
  const float* w_p  = (const float*)d_in[7];
  const float* g_p  = (const float*)d_in[8];
  const float* b_p  = (const float*)d_in[9];
  const float* w_c1 = (const float*)d_in[10];
  const float* g_c1 = (const float*)d_in[11];
  const float* b_c1 = (const float*)d_in[12];
  const float* w_c2 = (const float*)d_in[13];
  const float* g_c2 = (const float*)d_in[14];
  const float* b_c2 = (const float*)d_in[15];

  char* ws = (char*)d_ws;
  size_t off = 0;
  _Float16* x_pad = (_Float16*)(ws + off); off += XPAD_E * 2;
  _Float16* r_pad = (_Float16*)(ws + off); off += XPAD_E * 2;
  _Float16* wks   = (_Float16*)(ws + off); off += (size_t)5 * WSET * 2;
  _Float16* wuv   = (_Float16*)(ws + off); off += (size_t)6 * WUV_SET * 2;
  float*    u_pad = (float*)(ws + off);    off += UVP_E * 4;
  float*    v_pad = (float*)(ws + off);    off += UVP_E * 4;
  float*    u2    = (float*)(ws + off);    off += UV2_E * 4;
  float*    v2    = (float*)(ws + off);    off += UV2_E * 4;
  (void)ws_size; (void)in_sizes; (void)n_in; (void)out_size;

  hipMemsetAsync(u_pad, 0, UVP_E * 4, stream);     // atomicMax targets + zero pad
  hipMemsetAsync(v_pad, 0, UVP_E * 4, stream);

  k_border    <<<dim3(388, 8, 2), 256, 0, stream>>>(x_pad, r_pad);
  k_pack_x    <<<dim3(768, 8, 3), 256, 0, stream>>>(x, x_pad);
  k_repack_w  <<<dim3(256, 5),    256, 0, stream>>>(w_p1, g_p1, w_p2, g_p2, w_p, g_p,
                                                    w_c1, g_c1, w_c2, g_c2, wks);
  k_repack_uvw<<<dim3(256, 6),    256, 0, stream>>>(w_p, g_p, wuv);
  k_conv_p12  <<<1152, 256, 0, stream>>>(x_pad, wks, b_p1, b_p2, u_pad, v_pad);
  k_uv1d      <<<48,   256, 0, stream>>>(u_pad, v_pad, wuv, u2, v2);
  k_conv_c1f  <<<1152, 256, 0, stream>>>(x_pad, wks + (size_t)3 * WSET, b_p, b_c1,
                                         u2, v2, r_pad);
  k_conv_c2   <<<1152, 256, 0, stream>>>(r_pad, wks + (size_t)4 * WSET, b_c2,
                                         (float*)d_out);
}

// Round 5
// 555.725 us; speedup vs baseline: 1.1383x; 1.0087x over previous
//
#include <hip/hip_runtime.h>

// ct_layer round 12: Q16 core everywhere (p12 validated at 147us / MfmaUtil 54).
//   c1f/c2 ported from W4 (~170us each) to Q16 (32co x 256n waves, j=16 ->
//   weight L2 demand 52.7 B/cyc under the 56 B/cyc ceiling). Grid 576 =
//   288 spatial x 2 co-halves. Same tap order as W4 -> numerics unchanged.

typedef _Float16 f16x8 __attribute__((ext_vector_type(8)));
typedef _Float16 f16x4v __attribute__((ext_vector_type(4)));
typedef float f32x4 __attribute__((ext_vector_type(4)));

#define HP 98
#define WP 98
#define KTOT 2304
#define WSET (256*KTOT)                // 589824 elems per weight set
#define XPAD_E ((size_t)8*HP*WP*256)
#define UVP_E  ((size_t)8*98*256)      // u_pad/v_pad f32 (atomic targets)
#define UV2_E  ((size_t)3*8*96*256)    // u2/v2 f32 [case][b][pos][co]
#define WUV_SET 196608                 // 256co * 768k per (t,case)

// XCD-aware block swizzle (requires nwg % 8 == 0).
__device__ __forceinline__ int xcd_swz(int bid, int nwg)
{
  return (bid & 7) * (nwg >> 3) + (bid >> 3);
}

// ---------------- Q16 conv core: 32co x 256n per wave ---------------------
// Block = 4 waves x (2 cogs each) = 128 co x 256 n (16h x 16w tile).
// Halo 18x18 = 324 pos staged as 384 slots (24 KB), double-buffered.
// SW=0: halo h-major (lane=w, j=h); SW=1: w-major (lane=h, j=w).
// Both read: cache[r] = B[(r*18 + wl + o)*32 + quad*8]  (contiguous 1KB/instr).
#define BUF_Q 24576
#define SMEM_Q 49152

struct CtxQ {
  unsigned goff[6];
  unsigned lds_stage;
  unsigned aoff;
  int wl, quad, wv;
  int b, h0, w0;
};

template<int SW>
__device__ __forceinline__ CtxQ make_ctxQ(int spatial, int ch)
{
  CtxQ c;
  c.b = spatial / 36;
  const int tt = spatial - c.b * 36;
  const int ht = tt / 6, wt = tt - ht * 6;
  c.h0 = ht * 16; c.w0 = wt * 16;
  const int tid = threadIdx.x, lane = tid & 63;
  c.wv = tid >> 6;
  c.quad = lane >> 4; c.wl = lane & 15;
  c.aoff = (unsigned)((ch * 8 + c.wv * 2) * 512 + c.wl * 32 + c.quad * 8);
  const unsigned base_hw = (unsigned)(c.b * HP + c.h0) * WP + c.w0;
#pragma unroll
  for (int t = 0; t < 6; ++t) {
    int s = (c.wv * 6 + t) * 16 + (lane >> 2);   // 0..383; 324..383 dummy
    if (s > 323) s = 323;
    const int x = s / 18, y = s - x * 18;
    const int wh = SW ? y : x, ww = SW ? x : y;
    c.goff[t] = (base_hw + (unsigned)(wh * WP + ww)) * 256u + (lane & 3) * 8u;
  }
  c.lds_stage = (unsigned)(c.wv * 6) * 1024u + (unsigned)lane * 16u;
  return c;
}

__device__ __forceinline__ void stage_cbQ(const _Float16* __restrict__ src,
                                          char* sbuf, const CtxQ& c, int buf, int cb)
{
  char* l0 = sbuf + buf * BUF_Q + c.lds_stage;
#pragma unroll
  for (int t = 0; t < 6; ++t) {
    const _Float16* g = src + c.goff[t] + cb * 32;
    __builtin_amdgcn_global_load_lds(
        (const __attribute__((address_space(1))) void*)g,
        (__attribute__((address_space(3))) void*)(l0 + t * 1024), 16, 0, 0);
  }
}

// TR: tap = (TR==0) ? p*3+o : o*3+p  (weight layout tap = dh*3+dw).
template<int TR>
__device__ __forceinline__ void conv_accumQ(const _Float16* __restrict__ src,
                                            const _Float16* __restrict__ wkb,
                                            char* sbuf, const CtxQ& c, f32x4 acc[2][16])
{
  const _Float16* A0 = wkb + c.aoff;
  stage_cbQ(src, sbuf, c, 0, 0);
#pragma unroll 1
  for (int cb = 0; cb < 8; ++cb) {
    __syncthreads();
    if (cb < 7) stage_cbQ(src, sbuf, c, (cb + 1) & 1, cb + 1);
    const _Float16* B = (const _Float16*)(sbuf + (cb & 1) * BUF_Q);
    const _Float16* A = A0 + cb * (9 * 8192);
#pragma unroll
    for (int o = 0; o < 3; ++o) {
      f16x8 af[3][2];                              // hoisted across both jh halves
#pragma unroll
      for (int p = 0; p < 3; ++p) {
        const int tap = (TR == 0) ? p * 3 + o : o * 3 + p;
#pragma unroll
        for (int i = 0; i < 2; ++i)
          af[p][i] = *(const f16x8*)(A + tap * 8192 + i * 512);
      }
#pragma unroll
      for (int jh = 0; jh < 2; ++jh) {
        f16x8 cache[10];
#pragma unroll
        for (int r = 0; r < 10; ++r)
          cache[r] = *(const f16x8*)(B + ((jh * 8 + r) * 18 + c.wl + o) * 32 + c.quad * 8);
#pragma unroll
        for (int p = 0; p < 3; ++p)
#pragma unroll
          for (int i = 0; i < 2; ++i)
#pragma unroll
            for (int j = 0; j < 8; ++j)
              acc[i][jh * 8 + j] = __builtin_amdgcn_mfma_f32_16x16x32_f16(
                  af[p][i], cache[j + p], acc[i][jh * 8 + j], 0, 0, 0);
      }
    }
  }
  __syncthreads();
}

#define ZERO_ACCQ(acc) \
  _Pragma("unroll") for (int i = 0; i < 2; ++i) \
  _Pragma("unroll") for (int j = 0; j < 16; ++j) acc[i][j] = (f32x4){0.f,0.f,0.f,0.f};

// ---------------- p12: conv -> relu -> axis max -> atomicMax --------------
__global__ __launch_bounds__(256, 2) void k_conv_p12(
    const _Float16* __restrict__ xpad, const _Float16* __restrict__ wk,
    const float* __restrict__ bias1, const float* __restrict__ bias2,
    float* __restrict__ u_pad, float* __restrict__ v_pad)
{
  __shared__ __align__(16) char smem[SMEM_Q];
  const int lin = xcd_swz(blockIdx.x, 1152);
  const int set = lin >= 576;
  const int rem = lin - set * 576;
  const int spatial = rem >> 1, ch = rem & 1;
  f32x4 acc[2][16];
  ZERO_ACCQ(acc)
  if (set == 0) {
    CtxQ c = make_ctxQ<0>(spatial, ch);
    conv_accumQ<0>(xpad, wk, smem, c, acc);
#pragma unroll
    for (int i = 0; i < 2; ++i) {
      const int co = (ch * 8 + c.wv * 2 + i) * 16 + c.quad * 4;
      const float4 bs = *(const float4*)(bias1 + co);
      float m0 = 0.f, m1 = 0.f, m2 = 0.f, m3 = 0.f;
#pragma unroll
      for (int j = 0; j < 16; ++j) {               // j = h: in-lane max over h
        m0 = fmaxf(m0, acc[i][j][0] + bs.x);
        m1 = fmaxf(m1, acc[i][j][1] + bs.y);
        m2 = fmaxf(m2, acc[i][j][2] + bs.z);
        m3 = fmaxf(m3, acc[i][j][3] + bs.w);
      }
      unsigned* tgt = (unsigned*)(u_pad + ((size_t)c.b * 98 + (c.w0 + c.wl + 1)) * 256 + co);
      atomicMax(tgt + 0, __float_as_uint(m0));
      atomicMax(tgt + 1, __float_as_uint(m1));
      atomicMax(tgt + 2, __float_as_uint(m2));
      atomicMax(tgt + 3, __float_as_uint(m3));
    }
  } else {
    CtxQ c = make_ctxQ<1>(spatial, ch);
    conv_accumQ<1>(xpad, wk + WSET, smem, c, acc);
#pragma unroll
    for (int i = 0; i < 2; ++i) {
      const int co = (ch * 8 + c.wv * 2 + i) * 16 + c.quad * 4;
      const float4 bs = *(const float4*)(bias2 + co);
      float m0 = 0.f, m1 = 0.f, m2 = 0.f, m3 = 0.f;
#pragma unroll
      for (int j = 0; j < 16; ++j) {               // j = w: in-lane max over w
        m0 = fmaxf(m0, acc[i][j][0] + bs.x);
        m1 = fmaxf(m1, acc[i][j][1] + bs.y);
        m2 = fmaxf(m2, acc[i][j][2] + bs.z);
        m3 = fmaxf(m3, acc[i][j][3] + bs.w);
      }
      unsigned* tgt = (unsigned*)(v_pad + ((size_t)c.b * 98 + (c.h0 + c.wl + 1)) * 256 + co);
      atomicMax(tgt + 0, __float_as_uint(m0));
      atomicMax(tgt + 1, __float_as_uint(m1));
      atomicMax(tgt + 2, __float_as_uint(m2));
      atomicMax(tgt + 3, __float_as_uint(m3));
    }
  }
}

// ---------------- 1D convs of u,v with case-summed weights ----------------
__global__ __launch_bounds__(256, 2) void k_uv1d(
    const float* __restrict__ u_pad, const float* __restrict__ v_pad,
    const _Float16* __restrict__ wuv, float* __restrict__ u2, float* __restrict__ v2)
{
  const int id = blockIdx.x;
  const int b = id & 7, cs = (id >> 3) % 3, t = id / 24;
  const float* src = t ? v_pad : u_pad;
  float* dst = t ? v2 : u2;
  const _Float16* A0 = wuv + (size_t)(t * 3 + cs) * WUV_SET;
  const int lane = threadIdx.x & 63, wv = threadIdx.x >> 6;
  const int quad = lane >> 4, l16 = lane & 15;

  f32x4 acc[4][6];
#pragma unroll
  for (int i = 0; i < 4; ++i)
#pragma unroll
    for (int j = 0; j < 6; ++j) acc[i][j] = (f32x4){0.f, 0.f, 0.f, 0.f};

#pragma unroll 1
  for (int kb = 0; kb < 24; ++kb) {
    const int dw = kb >> 3, cb = kb & 7;
    f16x8 bf[6];
#pragma unroll
    for (int j = 0; j < 6; ++j) {
      const int pos = j * 16 + l16;
      const float* p = src + ((size_t)b * 98 + (pos + dw)) * 256 + cb * 32 + quad * 8;
      const float4 x0 = *(const float4*)p;
      const float4 x1 = *(const float4*)(p + 4);
      f16x8 v;
      v[0] = (_Float16)x0.x; v[1] = (_Float16)x0.y; v[2] = (_Float16)x0.z; v[3] = (_Float16)x0.w;
      v[4] = (_Float16)x1.x; v[5] = (_Float16)x1.y; v[6] = (_Float16)x1.z; v[7] = (_Float16)x1.w;
      bf[j] = v;
    }
    f16x8 af[4];
#pragma unroll
    for (int i = 0; i < 4; ++i)
      af[i] = *(const f16x8*)(A0 + (size_t)(kb * 16 + wv * 4 + i) * 512 + l16 * 32 + quad * 8);
#pragma unroll
    for (int i = 0; i < 4; ++i)
#pragma unroll
      for (int j = 0; j < 6; ++j)
        acc[i][j] = __builtin_amdgcn_mfma_f32_16x16x32_f16(af[i], bf[j], acc[i][j], 0, 0, 0);
  }
#pragma unroll
  for (int i = 0; i < 4; ++i)
#pragma unroll
    for (int j = 0; j < 6; ++j) {
      const int pos = j * 16 + l16;
      const int co = wv * 64 + i * 16 + quad * 4;
      *(f32x4*)(dst + ((size_t)(cs * 8 + b) * 96 + pos) * 256 + co) = acc[i][j];
    }
}

// ---------------- conv_c1 + U' + V' + biases, relu -> r_pad NHWC f16 ------
__global__ __launch_bounds__(256, 2) void k_conv_c1f(
    const _Float16* __restrict__ xpad, const _Float16* __restrict__ wkc1,
    const float* __restrict__ bias_p, const float* __restrict__ bias_c1,
    const float* __restrict__ u2, const float* __restrict__ v2,
    _Float16* __restrict__ rpad)
{
  __shared__ __align__(16) char smem[SMEM_Q];
  const int lin = xcd_swz(blockIdx.x, 576);
  const int spatial = lin >> 1, ch = lin & 1;
  CtxQ c = make_ctxQ<0>(spatial, ch);
  f32x4 acc[2][16];
  ZERO_ACCQ(acc)
  conv_accumQ<0>(xpad, wkc1, smem, c, acc);

  const int w = c.w0 + c.wl;
  const int wcase = (w == 0) ? 0 : ((w == 95) ? 2 : 1);
#pragma unroll
  for (int i = 0; i < 2; ++i) {
    const int co = (ch * 8 + c.wv * 2 + i) * 16 + c.quad * 4;
    float4 bs = *(const float4*)(bias_p + co);
    const float4 b2 = *(const float4*)(bias_c1 + co);
    bs.x += b2.x; bs.y += b2.y; bs.z += b2.z; bs.w += b2.w;
#pragma unroll
    for (int j = 0; j < 16; ++j) {
      const int h = c.h0 + j;
      const int hcase = (h == 0) ? 0 : ((h == 95) ? 2 : 1);
      const float4 uq = *(const float4*)(u2 + ((size_t)(hcase * 8 + c.b) * 96 + w) * 256 + co);
      const float4 vq = *(const float4*)(v2 + ((size_t)(wcase * 8 + c.b) * 96 + h) * 256 + co);
      f16x4v pk;
      pk[0] = (_Float16)fmaxf(acc[i][j][0] + bs.x + uq.x + vq.x, 0.f);
      pk[1] = (_Float16)fmaxf(acc[i][j][1] + bs.y + uq.y + vq.y, 0.f);
      pk[2] = (_Float16)fmaxf(acc[i][j][2] + bs.z + uq.z + vq.z, 0.f);
      pk[3] = (_Float16)fmaxf(acc[i][j][3] + bs.w + uq.w + vq.w, 0.f);
      *(f16x4v*)(rpad + ((size_t)(c.b * HP + h + 1) * WP + w + 1) * 256 + co) = pk;
    }
  }
}

// ---------------- final conv, relu, NCHW f32 to d_out ---------------------
__global__ __launch_bounds__(256, 2) void k_conv_c2(
    const _Float16* __restrict__ rpad, const _Float16* __restrict__ wkc2,
    const float* __restrict__ bias, float* __restrict__ dout)
{
  __shared__ __align__(16) char smem[SMEM_Q];
  const int lin = xcd_swz(blockIdx.x, 576);
  const int spatial = lin >> 1, ch = lin & 1;
  CtxQ c = make_ctxQ<0>(spatial, ch);
  f32x4 acc[2][16];
  ZERO_ACCQ(acc)
  conv_accumQ<0>(rpad, wkc2, smem, c, acc);

  const int w = c.w0 + c.wl;
#pragma unroll
  for (int j = 0; j < 16; ++j) {
    const int h = c.h0 + j;
    float* op = dout + (size_t)c.b * 2359296 + h * 96 + w;
#pragma unroll
    for (int i = 0; i < 2; ++i) {
      const int co = (ch * 8 + c.wv * 2 + i) * 16 + c.quad * 4;
      const float4 bs = *(const float4*)(bias + co);
      op[(size_t)(co + 0) * 9216] = fmaxf(acc[i][j][0] + bs.x, 0.f);
      op[(size_t)(co + 1) * 9216] = fmaxf(acc[i][j][1] + bs.y, 0.f);
      op[(size_t)(co + 2) * 9216] = fmaxf(acc[i][j][2] + bs.z, 0.f);
      op[(size_t)(co + 3) * 9216] = fmaxf(acc[i][j][3] + bs.w, 0.f);
    }
  }
}

// ---------------- aux kernels ---------------------------------------------
// Zero the 1-px halo ring of x_pad (z=0) and r_pad (z=1). 388 border pos/img.
__global__ void k_border(_Float16* __restrict__ xpad, _Float16* __restrict__ rpad)
{
  const int idx = blockIdx.x, b = blockIdx.y;
  _Float16* buf = blockIdx.z ? rpad : xpad;
  int h, w;
  if (idx < 98)       { h = 0;  w = idx; }
  else if (idx < 196) { h = 97; w = idx - 98; }
  else { const int r = idx - 196; h = 1 + (r >> 1); w = (r & 1) ? 97 : 0; }
  buf[((size_t)(b * HP + h) * WP + w) * 256 + threadIdx.x] = (_Float16)0.f;
}

__global__ void k_pack_x(const float* __restrict__ x, _Float16* __restrict__ xpad)
{
  __shared__ float tile[32][33];
  const int bh = blockIdx.x;
  const int b = bh / 96, h = bh - b * 96;
  const int c0 = blockIdx.y * 32, w0 = blockIdx.z * 32;
  const int tx = threadIdx.x & 31, ty = threadIdx.x >> 5;
#pragma unroll
  for (int i = 0; i < 4; ++i) {
    int cI = c0 + ty + i * 8;
    tile[ty + i * 8][tx] = x[(((size_t)b * 256 + cI) * 96 + h) * 96 + w0 + tx];
  }
  __syncthreads();
#pragma unroll
  for (int i = 0; i < 4; ++i) {
    int w = w0 + ty + i * 8;
    xpad[((size_t)(b * HP + h + 1) * WP + (w + 1)) * 256 + c0 + tx] =
        (_Float16)tile[tx][ty + i * 8];
  }
}

// main conv weights -> tiled layout: idx = ((cb*9+tap)*16 + cog)*512 + m*32 + kk
__global__ void k_repack_w(const float* w0, const float* g0, const float* w1, const float* g1,
                           const float* w2, const float* g2, const float* w3, const float* g3,
                           const float* w4, const float* g4, _Float16* __restrict__ wk)
{
  const int set = blockIdx.y;
  const float* w; const float* g;
  switch (set) {
    case 0: w = w0; g = g0; break;
    case 1: w = w1; g = g1; break;
    case 2: w = w2; g = g2; break;
    case 3: w = w3; g = g3; break;
    default: w = w4; g = g4; break;
  }
  const int t = blockIdx.x * 256 + threadIdx.x;   // co*256 + ci
  const int co = t >> 8, ci = t & 255;
  const int cb = ci >> 5, kk = ci & 31, cog = co >> 4, m = co & 15;
  const float gv = g[co];
  const float* src = w + ((size_t)co * 256 + ci) * 9;
  _Float16* dst = wk + (size_t)set * WSET + cog * 512 + m * 32 + kk;
#pragma unroll
  for (int tap = 0; tap < 9; ++tap)
    dst[(cb * 9 + tap) * 8192] = (_Float16)(src[tap] * gv);
}

// case-summed 1D weights for U'/V'
__global__ void k_repack_uvw(const float* __restrict__ wp, const float* __restrict__ gp,
                             _Float16* __restrict__ wuv)
{
  const int tcs = blockIdx.y;                             // 0..5 = t*3+cs
  const int tt = tcs / 3, cs = tcs - tt * 3;
  const int idx = blockIdx.x * 256 + threadIdx.x;         // co*256 + ci
  const int co = idx >> 8, ci = idx & 255;
  const float gv = gp[co];
  const float* src = wp + ((size_t)co * 256 + ci) * 9;    // [dh][dw]
  const int lo = (cs == 0) ? 1 : 0, hi = (cs == 2) ? 1 : 2;
  _Float16* base = wuv + (size_t)tcs * WUV_SET;
#pragma unroll
  for (int d = 0; d < 3; ++d) {
    float s = 0.f;
    for (int e = lo; e <= hi; ++e)
      s += (tt == 0) ? src[e * 3 + d] : src[d * 3 + e];
    const int k = d * 256 + ci;
    const int kb = k >> 5, kk = k & 31;
    base[(size_t)(kb * 16 + (co >> 4)) * 512 + (co & 15) * 32 + kk] = (_Float16)(s * gv);
  }
}

// ---------------- launcher -------------------------------------------------
extern "C" void kernel_launch(void* const* d_in, const int* in_sizes, int n_in,
                              void* d_out, int out_size, void* d_ws, size_t ws_size,
                              hipStream_t stream)
{
  const float* x    = (const float*)d_in[0];
  const float* w_p1 = (const float*)d_in[1];
  const float* g_p1 = (const float*)d_in[2];
  const float* b_p1 = (const float*)d_in[3];
  const float* w_p2 = (const float*)d_in[4];
  const float* g_p2 = (const float*)d_in[5];
  const float* b_p2 = (const float*)d_in[6];
  const float* w_p  = (const float*)d_in[7];
  const float* g_p  = (const float*)d_in[8];
  const float* b_p  = (const float*)d_in[9];
  const float* w_c1 = (const float*)d_in[10];
  const float* g_c1 = (const float*)d_in[11];
  const float* b_c1 = (const float*)d_in[12];
  const float* w_c2 = (const float*)d_in[13];
  const float* g_c2 = (const float*)d_in[14];
  const float* b_c2 = (const float*)d_in[15];

  char* ws = (char*)d_ws;
  size_t off = 0;
  _Float16* x_pad = (_Float16*)(ws + off); off += XPAD_E * 2;
  _Float16* r_pad = (_Float16*)(ws + off); off += XPAD_E * 2;
  _Float16* wks   = (_Float16*)(ws + off); off += (size_t)5 * WSET * 2;
  _Float16* wuv   = (_Float16*)(ws + off); off += (size_t)6 * WUV_SET * 2;
  float*    u_pad = (float*)(ws + off);    off += UVP_E * 4;
  float*    v_pad = (float*)(ws + off);    off += UVP_E * 4;
  float*    u2    = (float*)(ws + off);    off += UV2_E * 4;
  float*    v2    = (float*)(ws + off);    off += UV2_E * 4;
  (void)ws_size; (void)in_sizes; (void)n_in; (void)out_size;

  hipMemsetAsync(u_pad, 0, UVP_E * 4, stream);     // atomicMax targets + zero pad
  hipMemsetAsync(v_pad, 0, UVP_E * 4, stream);

  k_border    <<<dim3(388, 8, 2), 256, 0, stream>>>(x_pad, r_pad);
  k_pack_x    <<<dim3(768, 8, 3), 256, 0, stream>>>(x, x_pad);
  k_repack_w  <<<dim3(256, 5),    256, 0, stream>>>(w_p1, g_p1, w_p2, g_p2, w_p, g_p,
                                                    w_c1, g_c1, w_c2, g_c2, wks);
  k_repack_uvw<<<dim3(256, 6),    256, 0, stream>>>(w_p, g_p, wuv);
  k_conv_p12  <<<1152, 256, 0, stream>>>(x_pad, wks, b_p1, b_p2, u_pad, v_pad);
  k_uv1d      <<<48,   256, 0, stream>>>(u_pad, v_pad, wuv, u2, v2);
  k_conv_c1f  <<<576,  256, 0, stream>>>(x_pad, wks + (size_t)3 * WSET, b_p, b_c1,
                                         u2, v2, r_pad);
  k_conv_c2   <<<576,  256, 0, stream>>>(r_pad, wks + (size_t)4 * WSET, b_c2,
                                         (float*)d_out);
}

// Round 6
// 549.876 us; speedup vs baseline: 1.1504x; 1.0106x over previous
//
#include <hip/hip_runtime.h>

// ct_layer round 13: 2-wave co-quarter Q16 blocks ("Q16b") at 3 blocks/CU.
//   R12 post-mortem: c1f/c2 gained ~0 because grid tail dominates (576 blocks
//   @ 512 concurrent = 2 rounds for 1.125 rounds of work). Q16b: 64co x 256n
//   per 128-thread block (j=16 per wave preserved -> weight-L2 economics
//   intact), LDS 48KB x 3/CU -> 768 concurrent:
//     p12: 2304 blocks = exactly 3.0 rounds; c1f/c2: 1152 = 1.5 rounds.
//   Register discipline: goff[6] + carry/clamp mask derives the other 6 stage
//   addresses (+1 VGPR, not +6); __launch_bounds__(128,2) backstop.
//   uv1d: pos-split x2 (grid 48x2).

typedef _Float16 f16x8 __attribute__((ext_vector_type(8)));
typedef _Float16 f16x4v __attribute__((ext_vector_type(4)));
typedef float f32x4 __attribute__((ext_vector_type(4)));

#define HP 98
#define WP 98
#define KTOT 2304
#define WSET (256*KTOT)                // 589824 elems per weight set
#define XPAD_E ((size_t)8*HP*WP*256)
#define UVP_E  ((size_t)8*98*256)      // u_pad/v_pad f32 (atomic targets)
#define UV2_E  ((size_t)3*8*96*256)    // u2/v2 f32 [case][b][pos][co]
#define WUV_SET 196608                 // 256co * 768k per (t,case)

// XCD-aware block swizzle (requires nwg % 8 == 0).
__device__ __forceinline__ int xcd_swz(int bid, int nwg)
{
  return (bid & 7) * (nwg >> 3) + (bid >> 3);
}

// ---------------- Q16b conv core: 2 waves x (32co x 256n) -----------------
// Block = 128 threads, 64 co (ch quarter) x 256 n (16h x 16w tile).
// Halo 18x18 = 324 pos in 384 slots (24 KB), double-buffered (48 KB).
// SW=0: halo h-major (lane=w, j=h); SW=1: w-major (lane=h, j=w).
// Staging: wave wv covers slot-groups [wv*12, wv*12+12). Groups t<6 use
// cached goff[t]; groups t>=6 derive addr = goff[t-6] + delta (s -> s+96
// crosses rows as +5r+6c if y<12 else +6r-12c), clamped slots (s>323, dummy)
// reuse goff[t-6] (in-bounds, never read).
#define BUF_Q 24576
#define SMEM_Q 49152

struct CtxQ {
  unsigned goff[6];
  unsigned mask;                       // bits 0-5: y>=12 (delta sel); 6-11: dummy
  unsigned lds_stage;
  unsigned aoff;
  int wl, quad, wv;
  int b, h0, w0;
};

template<int SW>
__device__ __forceinline__ CtxQ make_ctxQ(int spatial, int ch)
{
  CtxQ c;
  c.b = spatial / 36;
  const int tt = spatial - c.b * 36;
  const int ht = tt / 6, wt = tt - ht * 6;
  c.h0 = ht * 16; c.w0 = wt * 16;
  const int tid = threadIdx.x, lane = tid & 63;
  c.wv = tid >> 6;                     // 0..1
  c.quad = lane >> 4; c.wl = lane & 15;
  c.aoff = (unsigned)((ch * 4 + c.wv * 2) * 512 + c.wl * 32 + c.quad * 8);
  const unsigned base_hw = (unsigned)(c.b * HP + c.h0) * WP + c.w0;
  const int lg = lane >> 2;            // 0..15 slot-in-group
  c.mask = 0;
#pragma unroll
  for (int t = 0; t < 6; ++t) {
    const int s = (c.wv * 12 + t) * 16 + lg;   // <= 287, no clamp needed
    const int x = s / 18, y = s - x * 18;
    const int wh = SW ? y : x, ww = SW ? x : y;
    c.goff[t] = (base_hw + (unsigned)(wh * WP + ww)) * 256u + (lane & 3) * 8u;
    if (y >= 12) c.mask |= (1u << t);
    if (s > 227) c.mask |= (1u << (6 + t));    // s+96 > 323 -> dummy slot
  }
  c.lds_stage = (unsigned)(c.wv * 12) * 1024u + (unsigned)lane * 16u;
  return c;
}

template<int SW>
__device__ __forceinline__ void stage_cbQ(const _Float16* __restrict__ src,
                                          char* sbuf, const CtxQ& c, int buf, int cb)
{
  constexpr int D0 = SW ? (6 * WP + 5) * 256 : (5 * WP + 6) * 256;
  constexpr int D1 = SW ? (6 - 12 * WP) * 256 : (6 * WP - 12) * 256;
  char* l0 = sbuf + buf * BUF_Q + c.lds_stage;
#pragma unroll
  for (int t = 0; t < 6; ++t) {
    const _Float16* g = src + c.goff[t] + cb * 32;
    __builtin_amdgcn_global_load_lds(
        (const __attribute__((address_space(1))) void*)g,
        (__attribute__((address_space(3))) void*)(l0 + t * 1024), 16, 0, 0);
  }
#pragma unroll
  for (int t = 0; t < 6; ++t) {
    const int d = ((c.mask >> (6 + t)) & 1) ? 0
                : (((c.mask >> t) & 1) ? D1 : D0);
    const _Float16* g = src + (int)(c.goff[t] + (unsigned)d) + cb * 32;
    __builtin_amdgcn_global_load_lds(
        (const __attribute__((address_space(1))) void*)g,
        (__attribute__((address_space(3))) void*)(l0 + (6 + t) * 1024), 16, 0, 0);
  }
}

// S: tap order (0: tap=p*3+o; 1: tap=o*3+p) and staging layout, always paired.
template<int S>
__device__ __forceinline__ void conv_accumQ(const _Float16* __restrict__ src,
                                            const _Float16* __restrict__ wkb,
                                            char* sbuf, const CtxQ& c, f32x4 acc[2][16])
{
  const _Float16* A0 = wkb + c.aoff;
  stage_cbQ<S>(src, sbuf, c, 0, 0);
#pragma unroll 1
  for (int cb = 0; cb < 8; ++cb) {
    __syncthreads();
    if (cb < 7) stage_cbQ<S>(src, sbuf, c, (cb + 1) & 1, cb + 1);
    const _Float16* B = (const _Float16*)(sbuf + (cb & 1) * BUF_Q);
    const _Float16* A = A0 + cb * (9 * 8192);
#pragma unroll
    for (int o = 0; o < 3; ++o) {
      f16x8 af[3][2];                            // hoisted across both jh halves
#pragma unroll
      for (int p = 0; p < 3; ++p) {
        const int tap = (S == 0) ? p * 3 + o : o * 3 + p;
#pragma unroll
        for (int i = 0; i < 2; ++i)
          af[p][i] = *(const f16x8*)(A + tap * 8192 + i * 512);
      }
#pragma unroll
      for (int jh = 0; jh < 2; ++jh) {
        f16x8 cache[10];
#pragma unroll
        for (int r = 0; r < 10; ++r)
          cache[r] = *(const f16x8*)(B + ((jh * 8 + r) * 18 + c.wl + o) * 32 + c.quad * 8);
#pragma unroll
        for (int p = 0; p < 3; ++p)
#pragma unroll
          for (int i = 0; i < 2; ++i)
#pragma unroll
            for (int j = 0; j < 8; ++j)
              acc[i][jh * 8 + j] = __builtin_amdgcn_mfma_f32_16x16x32_f16(
                  af[p][i], cache[j + p], acc[i][jh * 8 + j], 0, 0, 0);
      }
    }
  }
  __syncthreads();
}

#define ZERO_ACCQ(acc) \
  _Pragma("unroll") for (int i = 0; i < 2; ++i) \
  _Pragma("unroll") for (int j = 0; j < 16; ++j) acc[i][j] = (f32x4){0.f,0.f,0.f,0.f};

// ---------------- p12: conv -> relu -> axis max -> atomicMax --------------
__global__ __launch_bounds__(128, 2) void k_conv_p12(
    const _Float16* __restrict__ xpad, const _Float16* __restrict__ wk,
    const float* __restrict__ bias1, const float* __restrict__ bias2,
    float* __restrict__ u_pad, float* __restrict__ v_pad)
{
  __shared__ __align__(16) char smem[SMEM_Q];
  const int lin = xcd_swz(blockIdx.x, 2304);
  const int set = lin >= 1152;
  const int rem = lin - set * 1152;
  const int spatial = rem >> 2, ch = rem & 3;
  f32x4 acc[2][16];
  ZERO_ACCQ(acc)
  if (set == 0) {
    CtxQ c = make_ctxQ<0>(spatial, ch);
    conv_accumQ<0>(xpad, wk, smem, c, acc);
#pragma unroll
    for (int i = 0; i < 2; ++i) {
      const int co = (ch * 4 + c.wv * 2 + i) * 16 + c.quad * 4;
      const float4 bs = *(const float4*)(bias1 + co);
      float m0 = 0.f, m1 = 0.f, m2 = 0.f, m3 = 0.f;
#pragma unroll
      for (int j = 0; j < 16; ++j) {             // j = h: in-lane max over h
        m0 = fmaxf(m0, acc[i][j][0] + bs.x);
        m1 = fmaxf(m1, acc[i][j][1] + bs.y);
        m2 = fmaxf(m2, acc[i][j][2] + bs.z);
        m3 = fmaxf(m3, acc[i][j][3] + bs.w);
      }
      unsigned* tgt = (unsigned*)(u_pad + ((size_t)c.b * 98 + (c.w0 + c.wl + 1)) * 256 + co);
      atomicMax(tgt + 0, __float_as_uint(m0));
      atomicMax(tgt + 1, __float_as_uint(m1));
      atomicMax(tgt + 2, __float_as_uint(m2));
      atomicMax(tgt + 3, __float_as_uint(m3));
    }
  } else {
    CtxQ c = make_ctxQ<1>(spatial, ch);
    conv_accumQ<1>(xpad, wk + WSET, smem, c, acc);
#pragma unroll
    for (int i = 0; i < 2; ++i) {
      const int co = (ch * 4 + c.wv * 2 + i) * 16 + c.quad * 4;
      const float4 bs = *(const float4*)(bias2 + co);
      float m0 = 0.f, m1 = 0.f, m2 = 0.f, m3 = 0.f;
#pragma unroll
      for (int j = 0; j < 16; ++j) {             // j = w: in-lane max over w
        m0 = fmaxf(m0, acc[i][j][0] + bs.x);
        m1 = fmaxf(m1, acc[i][j][1] + bs.y);
        m2 = fmaxf(m2, acc[i][j][2] + bs.z);
        m3 = fmaxf(m3, acc[i][j][3] + bs.w);
      }
      unsigned* tgt = (unsigned*)(v_pad + ((size_t)c.b * 98 + (c.h0 + c.wl + 1)) * 256 + co);
      atomicMax(tgt + 0, __float_as_uint(m0));
      atomicMax(tgt + 1, __float_as_uint(m1));
      atomicMax(tgt + 2, __float_as_uint(m2));
      atomicMax(tgt + 3, __float_as_uint(m3));
    }
  }
}

// ---------------- 1D convs of u,v with case-summed weights ----------------
__global__ __launch_bounds__(256, 2) void k_uv1d(
    const float* __restrict__ u_pad, const float* __restrict__ v_pad,
    const _Float16* __restrict__ wuv, float* __restrict__ u2, float* __restrict__ v2)
{
  const int id = blockIdx.x;
  const int py = blockIdx.y;                     // 0..1 pos half
  const int b = id & 7, cs = (id >> 3) % 3, t = id / 24;
  const float* src = t ? v_pad : u_pad;
  float* dst = t ? v2 : u2;
  const _Float16* A0 = wuv + (size_t)(t * 3 + cs) * WUV_SET;
  const int lane = threadIdx.x & 63, wv = threadIdx.x >> 6;
  const int quad = lane >> 4, l16 = lane & 15;

  f32x4 acc[4][3];
#pragma unroll
  for (int i = 0; i < 4; ++i)
#pragma unroll
    for (int j = 0; j < 3; ++j) acc[i][j] = (f32x4){0.f, 0.f, 0.f, 0.f};

#pragma unroll 1
  for (int kb = 0; kb < 24; ++kb) {
    const int dw = kb >> 3, cb = kb & 7;
    f16x8 bf[3];
#pragma unroll
    for (int j = 0; j < 3; ++j) {
      const int pos = py * 48 + j * 16 + l16;
      const float* p = src + ((size_t)b * 98 + (pos + dw)) * 256 + cb * 32 + quad * 8;
      const float4 x0 = *(const float4*)p;
      const float4 x1 = *(const float4*)(p + 4);
      f16x8 v;
      v[0] = (_Float16)x0.x; v[1] = (_Float16)x0.y; v[2] = (_Float16)x0.z; v[3] = (_Float16)x0.w;
      v[4] = (_Float16)x1.x; v[5] = (_Float16)x1.y; v[6] = (_Float16)x1.z; v[7] = (_Float16)x1.w;
      bf[j] = v;
    }
    f16x8 af[4];
#pragma unroll
    for (int i = 0; i < 4; ++i)
      af[i] = *(const f16x8*)(A0 + (size_t)(kb * 16 + wv * 4 + i) * 512 + l16 * 32 + quad * 8);
#pragma unroll
    for (int i = 0; i < 4; ++i)
#pragma unroll
      for (int j = 0; j < 3; ++j)
        acc[i][j] = __builtin_amdgcn_mfma_f32_16x16x32_f16(af[i], bf[j], acc[i][j], 0, 0, 0);
  }
#pragma unroll
  for (int i = 0; i < 4; ++i)
#pragma unroll
    for (int j = 0; j < 3; ++j) {
      const int pos = py * 48 + j * 16 + l16;
      const int co = wv * 64 + i * 16 + quad * 4;
      *(f32x4*)(dst + ((size_t)(cs * 8 + b) * 96 + pos) * 256 + co) = acc[i][j];
    }
}

// ---------------- conv_c1 + U' + V' + biases, relu -> r_pad NHWC f16 ------
__global__ __launch_bounds__(128, 2) void k_conv_c1f(
    const _Float16* __restrict__ xpad, const _Float16* __restrict__ wkc1,
    const float* __restrict__ bias_p, const float* __restrict__ bias_c1,
    const float* __restrict__ u2, const float* __restrict__ v2,
    _Float16* __restrict__ rpad)
{
  __shared__ __align__(16) char smem[SMEM_Q];
  const int lin = xcd_swz(blockIdx.x, 1152);
  const int spatial = lin >> 2, ch = lin & 3;
  CtxQ c = make_ctxQ<0>(spatial, ch);
  f32x4 acc[2][16];
  ZERO_ACCQ(acc)
  conv_accumQ<0>(xpad, wkc1, smem, c, acc);

  const int w = c.w0 + c.wl;
  const int wcase = (w == 0) ? 0 : ((w == 95) ? 2 : 1);
#pragma unroll
  for (int i = 0; i < 2; ++i) {
    const int co = (ch * 4 + c.wv * 2 + i) * 16 + c.quad * 4;
    float4 bs = *(const float4*)(bias_p + co);
    const float4 b2 = *(const float4*)(bias_c1 + co);
    bs.x += b2.x; bs.y += b2.y; bs.z += b2.z; bs.w += b2.w;
#pragma unroll
    for (int j = 0; j < 16; ++j) {
      const int h = c.h0 + j;
      const int hcase = (h == 0) ? 0 : ((h == 95) ? 2 : 1);
      const float4 uq = *(const float4*)(u2 + ((size_t)(hcase * 8 + c.b) * 96 + w) * 256 + co);
      const float4 vq = *(const float4*)(v2 + ((size_t)(wcase * 8 + c.b) * 96 + h) * 256 + co);
      f16x4v pk;
      pk[0] = (_Float16)fmaxf(acc[i][j][0] + bs.x + uq.x + vq.x, 0.f);
      pk[1] = (_Float16)fmaxf(acc[i][j][1] + bs.y + uq.y + vq.y, 0.f);
      pk[2] = (_Float16)fmaxf(acc[i][j][2] + bs.z + uq.z + vq.z, 0.f);
      pk[3] = (_Float16)fmaxf(acc[i][j][3] + bs.w + uq.w + vq.w, 0.f);
      *(f16x4v*)(rpad + ((size_t)(c.b * HP + h + 1) * WP + w + 1) * 256 + co) = pk;
    }
  }
}

// ---------------- final conv, relu, NCHW f32 to d_out ---------------------
__global__ __launch_bounds__(128, 2) void k_conv_c2(
    const _Float16* __restrict__ rpad, const _Float16* __restrict__ wkc2,
    const float* __restrict__ bias, float* __restrict__ dout)
{
  __shared__ __align__(16) char smem[SMEM_Q];
  const int lin = xcd_swz(blockIdx.x, 1152);
  const int spatial = lin >> 2, ch = lin & 3;
  CtxQ c = make_ctxQ<0>(spatial, ch);
  f32x4 acc[2][16];
  ZERO_ACCQ(acc)
  conv_accumQ<0>(rpad, wkc2, smem, c, acc);

  const int w = c.w0 + c.wl;
#pragma unroll
  for (int j = 0; j < 16; ++j) {
    const int h = c.h0 + j;
    float* op = dout + (size_t)c.b * 2359296 + h * 96 + w;
#pragma unroll
    for (int i = 0; i < 2; ++i) {
      const int co = (ch * 4 + c.wv * 2 + i) * 16 + c.quad * 4;
      const float4 bs = *(const float4*)(bias + co);
      op[(size_t)(co + 0) * 9216] = fmaxf(acc[i][j][0] + bs.x, 0.f);
      op[(size_t)(co + 1) * 9216] = fmaxf(acc[i][j][1] + bs.y, 0.f);
      op[(size_t)(co + 2) * 9216] = fmaxf(acc[i][j][2] + bs.z, 0.f);
      op[(size_t)(co + 3) * 9216] = fmaxf(acc[i][j][3] + bs.w, 0.f);
    }
  }
}

// ---------------- aux kernels ---------------------------------------------
// Zero the 1-px halo ring of x_pad (z=0) and r_pad (z=1). 388 border pos/img.
__global__ void k_border(_Float16* __restrict__ xpad, _Float16* __restrict__ rpad)
{
  const int idx = blockIdx.x, b = blockIdx.y;
  _Float16* buf = blockIdx.z ? rpad : xpad;
  int h, w;
  if (idx < 98)       { h = 0;  w = idx; }
  else if (idx < 196) { h = 97; w = idx - 98; }
  else { const int r = idx - 196; h = 1 + (r >> 1); w = (r & 1) ? 97 : 0; }
  buf[((size_t)(b * HP + h) * WP + w) * 256 + threadIdx.x] = (_Float16)0.f;
}

__global__ void k_pack_x(const float* __restrict__ x, _Float16* __restrict__ xpad)
{
  __shared__ float tile[32][33];
  const int bh = blockIdx.x;
  const int b = bh / 96, h = bh - b * 96;
  const int c0 = blockIdx.y * 32, w0 = blockIdx.z * 32;
  const int tx = threadIdx.x & 31, ty = threadIdx.x >> 5;
#pragma unroll
  for (int i = 0; i < 4; ++i) {
    int cI = c0 + ty + i * 8;
    tile[ty + i * 8][tx] = x[(((size_t)b * 256 + cI) * 96 + h) * 96 + w0 + tx];
  }
  __syncthreads();
#pragma unroll
  for (int i = 0; i < 4; ++i) {
    int w = w0 + ty + i * 8;
    xpad[((size_t)(b * HP + h + 1) * WP + (w + 1)) * 256 + c0 + tx] =
        (_Float16)tile[tx][ty + i * 8];
  }
}

// main conv weights -> tiled layout: idx = ((cb*9+tap)*16 + cog)*512 + m*32 + kk
__global__ void k_repack_w(const float* w0, const float* g0, const float* w1, const float* g1,
                           const float* w2, const float* g2, const float* w3, const float* g3,
                           const float* w4, const float* g4, _Float16* __restrict__ wk)
{
  const int set = blockIdx.y;
  const float* w; const float* g;
  switch (set) {
    case 0: w = w0; g = g0; break;
    case 1: w = w1; g = g1; break;
    case 2: w = w2; g = g2; break;
    case 3: w = w3; g = g3; break;
    default: w = w4; g = g4; break;
  }
  const int t = blockIdx.x * 256 + threadIdx.x;   // co*256 + ci
  const int co = t >> 8, ci = t & 255;
  const int cb = ci >> 5, kk = ci & 31, cog = co >> 4, m = co & 15;
  const float gv = g[co];
  const float* src = w + ((size_t)co * 256 + ci) * 9;
  _Float16* dst = wk + (size_t)set * WSET + cog * 512 + m * 32 + kk;
#pragma unroll
  for (int tap = 0; tap < 9; ++tap)
    dst[(cb * 9 + tap) * 8192] = (_Float16)(src[tap] * gv);
}

// case-summed 1D weights for U'/V'
__global__ void k_repack_uvw(const float* __restrict__ wp, const float* __restrict__ gp,
                             _Float16* __restrict__ wuv)
{
  const int tcs = blockIdx.y;                             // 0..5 = t*3+cs
  const int tt = tcs / 3, cs = tcs - tt * 3;
  const int idx = blockIdx.x * 256 + threadIdx.x;         // co*256 + ci
  const int co = idx >> 8, ci = idx & 255;
  const float gv = gp[co];
  const float* src = wp + ((size_t)co * 256 + ci) * 9;    // [dh][dw]
  const int lo = (cs == 0) ? 1 : 0, hi = (cs == 2) ? 1 : 2;
  _Float16* base = wuv + (size_t)tcs * WUV_SET;
#pragma unroll
  for (int d = 0; d < 3; ++d) {
    float s = 0.f;
    for (int e = lo; e <= hi; ++e)
      s += (tt == 0) ? src[e * 3 + d] : src[d * 3 + e];
    const int k = d * 256 + ci;
    const int kb = k >> 5, kk = k & 31;
    base[(size_t)(kb * 16 + (co >> 4)) * 512 + (co & 15) * 32 + kk] = (_Float16)(s * gv);
  }
}

// ---------------- launcher -------------------------------------------------
extern "C" void kernel_launch(void* const* d_in, const int* in_sizes, int n_in,
                              void* d_out, int out_size, void* d_ws, size_t ws_size,
                              hipStream_t stream)
{
  const float* x    = (const float*)d_in[0];
  const float* w_p1 = (const float*)d_in[1];
  const float* g_p1 = (const float*)d_in[2];
  const float* b_p1 = (const float*)d_in[3];
  const float* w_p2 = (const float*)d_in[4];
  const float* g_p2 = (const float*)d_in[5];
  const float* b_p2 = (const float*)d_in[6];
  const float* w_p  = (const float*)d_in[7];
  const float* g_p  = (const float*)d_in[8];
  const float* b_p  = (const float*)d_in[9];
  const float* w_c1 = (const float*)d_in[10];
  const float* g_c1 = (const float*)d_in[11];
  const float* b_c1 = (const float*)d_in[12];
  const float* w_c2 = (const float*)d_in[13];
  const float* g_c2 = (const float*)d_in[14];
  const float* b_c2 = (const float*)d_in[15];

  char* ws = (char*)d_ws;
  size_t off = 0;
  _Float16* x_pad = (_Float16*)(ws + off); off += XPAD_E * 2;
  _Float16* r_pad = (_Float16*)(ws + off); off += XPAD_E * 2;
  _Float16* wks   = (_Float16*)(ws + off); off += (size_t)5 * WSET * 2;
  _Float16* wuv   = (_Float16*)(ws + off); off += (size_t)6 * WUV_SET * 2;
  float*    u_pad = (float*)(ws + off);    off += UVP_E * 4;
  float*    v_pad = (float*)(ws + off);    off += UVP_E * 4;
  float*    u2    = (float*)(ws + off);    off += UV2_E * 4;
  float*    v2    = (float*)(ws + off);    off += UV2_E * 4;
  (void)ws_size; (void)in_sizes; (void)n_in; (void)out_size;

  hipMemsetAsync(u_pad, 0, UVP_E * 4, stream);     // atomicMax targets + zero pad
  hipMemsetAsync(v_pad, 0, UVP_E * 4, stream);

  k_border    <<<dim3(388, 8, 2), 256, 0, stream>>>(x_pad, r_pad);
  k_pack_x    <<<dim3(768, 8, 3), 256, 0, stream>>>(x, x_pad);
  k_repack_w  <<<dim3(256, 5),    256, 0, stream>>>(w_p1, g_p1, w_p2, g_p2, w_p, g_p,
                                                    w_c1, g_c1, w_c2, g_c2, wks);
  k_repack_uvw<<<dim3(256, 6),    256, 0, stream>>>(w_p, g_p, wuv);
  k_conv_p12  <<<2304, 128, 0, stream>>>(x_pad, wks, b_p1, b_p2, u_pad, v_pad);
  k_uv1d      <<<dim3(48, 2), 256, 0, stream>>>(u_pad, v_pad, wuv, u2, v2);
  k_conv_c1f  <<<1152, 128, 0, stream>>>(x_pad, wks + (size_t)3 * WSET, b_p, b_c1,
                                         u2, v2, r_pad);
  k_conv_c2   <<<1152, 128, 0, stream>>>(r_pad, wks + (size_t)4 * WSET, b_c2,
                                         (float*)d_out);
}

// Round 7
// 522.045 us; speedup vs baseline: 1.2117x; 1.0533x over previous
//
#include <hip/hip_runtime.h>

// ct_layer round 14: consolidation + p12/c1conv grid fusion.
//   R13 post-mortem: Q16b halved per-block MFMA but not staging (24KB/cb
//   either way) -> block time ~constant -> p12 regressed. 4-wave Q16 (128co
//   per staged halo) is the staging-amortization sweet spot.
//   - p12: back to R12 4-wave Q16 (measured 145us, MfmaUtil 54).
//   - c1 conv is p12-independent (only its +U'+V' epilogue needs uv1d):
//     merged into one kernel, grid 1152 p12-items + 576 c1conv-items = 1728
//     @ 512 concurrent = 4 rounds vs 3+2=5 separate. c1conv writes
//     f16(acc+bias) to tmp carved from d_out (free until c2).
//   - k_epi_c1: coalesced +U'+V'+relu -> r_pad (~15us), after uv1d.
//   - c2: keep R13 2-wave Q16b (measured better for c-convs).

typedef _Float16 f16x8 __attribute__((ext_vector_type(8)));
typedef _Float16 f16x4v __attribute__((ext_vector_type(4)));
typedef float f32x4 __attribute__((ext_vector_type(4)));

#define HP 98
#define WP 98
#define KTOT 2304
#define WSET (256*KTOT)                // 589824 elems per weight set
#define XPAD_E ((size_t)8*HP*WP*256)
#define UVP_E  ((size_t)8*98*256)      // u_pad/v_pad f32 (atomic targets)
#define UV2_E  ((size_t)3*8*96*256)    // u2/v2 f32 [case][b][pos][co]
#define WUV_SET 196608                 // 256co * 768k per (t,case)

// XCD-aware block swizzle (requires nwg % 8 == 0).
__device__ __forceinline__ int xcd_swz(int bid, int nwg)
{
  return (bid & 7) * (nwg >> 3) + (bid >> 3);
}

// ---------------- Q16 conv core (4-wave): 32co x 256n per wave ------------
// Block = 4 waves x (2 cogs each) = 128 co x 256 n (16h x 16w tile).
// Halo 18x18 = 324 pos staged as 384 slots (24 KB), double-buffered.
// SW=0: halo h-major (lane=w, j=h); SW=1: w-major (lane=h, j=w).
#define BUF_Q 24576
#define SMEM_Q 49152

struct CtxQ {
  unsigned goff[6];
  unsigned lds_stage;
  unsigned aoff;
  int wl, quad, wv;
  int b, h0, w0;
};

template<int SW>
__device__ __forceinline__ CtxQ make_ctxQ(int spatial, int ch)
{
  CtxQ c;
  c.b = spatial / 36;
  const int tt = spatial - c.b * 36;
  const int ht = tt / 6, wt = tt - ht * 6;
  c.h0 = ht * 16; c.w0 = wt * 16;
  const int tid = threadIdx.x, lane = tid & 63;
  c.wv = tid >> 6;
  c.quad = lane >> 4; c.wl = lane & 15;
  c.aoff = (unsigned)((ch * 8 + c.wv * 2) * 512 + c.wl * 32 + c.quad * 8);
  const unsigned base_hw = (unsigned)(c.b * HP + c.h0) * WP + c.w0;
#pragma unroll
  for (int t = 0; t < 6; ++t) {
    int s = (c.wv * 6 + t) * 16 + (lane >> 2);   // 0..383; 324..383 dummy
    if (s > 323) s = 323;
    const int x = s / 18, y = s - x * 18;
    const int wh = SW ? y : x, ww = SW ? x : y;
    c.goff[t] = (base_hw + (unsigned)(wh * WP + ww)) * 256u + (lane & 3) * 8u;
  }
  c.lds_stage = (unsigned)(c.wv * 6) * 1024u + (unsigned)lane * 16u;
  return c;
}

__device__ __forceinline__ void stage_cbQ(const _Float16* __restrict__ src,
                                          char* sbuf, const CtxQ& c, int buf, int cb)
{
  char* l0 = sbuf + buf * BUF_Q + c.lds_stage;
#pragma unroll
  for (int t = 0; t < 6; ++t) {
    const _Float16* g = src + c.goff[t] + cb * 32;
    __builtin_amdgcn_global_load_lds(
        (const __attribute__((address_space(1))) void*)g,
        (__attribute__((address_space(3))) void*)(l0 + t * 1024), 16, 0, 0);
  }
}

// S: tap = (S==0) ? p*3+o : o*3+p  (weight layout tap = dh*3+dw).
template<int S>
__device__ __forceinline__ void conv_accumQ(const _Float16* __restrict__ src,
                                            const _Float16* __restrict__ wkb,
                                            char* sbuf, const CtxQ& c, f32x4 acc[2][16])
{
  const _Float16* A0 = wkb + c.aoff;
  stage_cbQ(src, sbuf, c, 0, 0);
#pragma unroll 1
  for (int cb = 0; cb < 8; ++cb) {
    __syncthreads();
    if (cb < 7) stage_cbQ(src, sbuf, c, (cb + 1) & 1, cb + 1);
    const _Float16* B = (const _Float16*)(sbuf + (cb & 1) * BUF_Q);
    const _Float16* A = A0 + cb * (9 * 8192);
#pragma unroll
    for (int o = 0; o < 3; ++o) {
      f16x8 af[3][2];                              // hoisted across both jh halves
#pragma unroll
      for (int p = 0; p < 3; ++p) {
        const int tap = (S == 0) ? p * 3 + o : o * 3 + p;
#pragma unroll
        for (int i = 0; i < 2; ++i)
          af[p][i] = *(const f16x8*)(A + tap * 8192 + i * 512);
      }
#pragma unroll
      for (int jh = 0; jh < 2; ++jh) {
        f16x8 cache[10];
#pragma unroll
        for (int r = 0; r < 10; ++r)
          cache[r] = *(const f16x8*)(B + ((jh * 8 + r) * 18 + c.wl + o) * 32 + c.quad * 8);
#pragma unroll
        for (int p = 0; p < 3; ++p)
#pragma unroll
          for (int i = 0; i < 2; ++i)
#pragma unroll
            for (int j = 0; j < 8; ++j)
              acc[i][jh * 8 + j] = __builtin_amdgcn_mfma_f32_16x16x32_f16(
                  af[p][i], cache[j + p], acc[i][jh * 8 + j], 0, 0, 0);
      }
    }
  }
  __syncthreads();
}

#define ZERO_ACCQ(acc) \
  _Pragma("unroll") for (int i = 0; i < 2; ++i) \
  _Pragma("unroll") for (int j = 0; j < 16; ++j) acc[i][j] = (f32x4){0.f,0.f,0.f,0.f};

// ---------------- Q16b conv core (2-wave, for c2): 64co x 256n per block --
struct CtxB {
  unsigned goff[6];
  unsigned mask;                       // bits 0-5: y>=12 (delta sel); 6-11: dummy
  unsigned lds_stage;
  unsigned aoff;
  int wl, quad, wv;
  int b, h0, w0;
};

template<int SW>
__device__ __forceinline__ CtxB make_ctxB(int spatial, int ch)
{
  CtxB c;
  c.b = spatial / 36;
  const int tt = spatial - c.b * 36;
  const int ht = tt / 6, wt = tt - ht * 6;
  c.h0 = ht * 16; c.w0 = wt * 16;
  const int tid = threadIdx.x, lane = tid & 63;
  c.wv = tid >> 6;                     // 0..1
  c.quad = lane >> 4; c.wl = lane & 15;
  c.aoff = (unsigned)((ch * 4 + c.wv * 2) * 512 + c.wl * 32 + c.quad * 8);
  const unsigned base_hw = (unsigned)(c.b * HP + c.h0) * WP + c.w0;
  const int lg = lane >> 2;            // 0..15 slot-in-group
  c.mask = 0;
#pragma unroll
  for (int t = 0; t < 6; ++t) {
    const int s = (c.wv * 12 + t) * 16 + lg;   // <= 287, no clamp needed
    const int x = s / 18, y = s - x * 18;
    const int wh = SW ? y : x, ww = SW ? x : y;
    c.goff[t] = (base_hw + (unsigned)(wh * WP + ww)) * 256u + (lane & 3) * 8u;
    if (y >= 12) c.mask |= (1u << t);
    if (s > 227) c.mask |= (1u << (6 + t));    // s+96 > 323 -> dummy slot
  }
  c.lds_stage = (unsigned)(c.wv * 12) * 1024u + (unsigned)lane * 16u;
  return c;
}

template<int SW>
__device__ __forceinline__ void stage_cbB(const _Float16* __restrict__ src,
                                          char* sbuf, const CtxB& c, int buf, int cb)
{
  constexpr int D0 = SW ? (6 * WP + 5) * 256 : (5 * WP + 6) * 256;
  constexpr int D1 = SW ? (6 - 12 * WP) * 256 : (6 * WP - 12) * 256;
  char* l0 = sbuf + buf * BUF_Q + c.lds_stage;
#pragma unroll
  for (int t = 0; t < 6; ++t) {
    const _Float16* g = src + c.goff[t] + cb * 32;
    __builtin_amdgcn_global_load_lds(
        (const __attribute__((address_space(1))) void*)g,
        (__attribute__((address_space(3))) void*)(l0 + t * 1024), 16, 0, 0);
  }
#pragma unroll
  for (int t = 0; t < 6; ++t) {
    const int d = ((c.mask >> (6 + t)) & 1) ? 0
                : (((c.mask >> t) & 1) ? D1 : D0);
    const _Float16* g = src + (int)(c.goff[t] + (unsigned)d) + cb * 32;
    __builtin_amdgcn_global_load_lds(
        (const __attribute__((address_space(1))) void*)g,
        (__attribute__((address_space(3))) void*)(l0 + (6 + t) * 1024), 16, 0, 0);
  }
}

template<int S>
__device__ __forceinline__ void conv_accumB(const _Float16* __restrict__ src,
                                            const _Float16* __restrict__ wkb,
                                            char* sbuf, const CtxB& c, f32x4 acc[2][16])
{
  const _Float16* A0 = wkb + c.aoff;
  stage_cbB<S>(src, sbuf, c, 0, 0);
#pragma unroll 1
  for (int cb = 0; cb < 8; ++cb) {
    __syncthreads();
    if (cb < 7) stage_cbB<S>(src, sbuf, c, (cb + 1) & 1, cb + 1);
    const _Float16* B = (const _Float16*)(sbuf + (cb & 1) * BUF_Q);
    const _Float16* A = A0 + cb * (9 * 8192);
#pragma unroll
    for (int o = 0; o < 3; ++o) {
      f16x8 af[3][2];
#pragma unroll
      for (int p = 0; p < 3; ++p) {
        const int tap = (S == 0) ? p * 3 + o : o * 3 + p;
#pragma unroll
        for (int i = 0; i < 2; ++i)
          af[p][i] = *(const f16x8*)(A + tap * 8192 + i * 512);
      }
#pragma unroll
      for (int jh = 0; jh < 2; ++jh) {
        f16x8 cache[10];
#pragma unroll
        for (int r = 0; r < 10; ++r)
          cache[r] = *(const f16x8*)(B + ((jh * 8 + r) * 18 + c.wl + o) * 32 + c.quad * 8);
#pragma unroll
        for (int p = 0; p < 3; ++p)
#pragma unroll
          for (int i = 0; i < 2; ++i)
#pragma unroll
            for (int j = 0; j < 8; ++j)
              acc[i][jh * 8 + j] = __builtin_amdgcn_mfma_f32_16x16x32_f16(
                  af[p][i], cache[j + p], acc[i][jh * 8 + j], 0, 0, 0);
      }
    }
  }
  __syncthreads();
}

// ---------------- merged main conv: p12 (1152 items) + c1conv (576) -------
__global__ __launch_bounds__(256, 2) void k_conv_main(
    const _Float16* __restrict__ xpad, const _Float16* __restrict__ wk,
    const float* __restrict__ bias1, const float* __restrict__ bias2,
    const float* __restrict__ bias_p, const float* __restrict__ bias_c1,
    float* __restrict__ u_pad, float* __restrict__ v_pad,
    _Float16* __restrict__ tmp)
{
  __shared__ __align__(16) char smem[SMEM_Q];
  const int lin = xcd_swz(blockIdx.x, 1728);
  f32x4 acc[2][16];
  ZERO_ACCQ(acc)
  if (lin < 1152) {
    const int set = lin >= 576;
    const int rem = lin - set * 576;
    const int spatial = rem >> 1, ch = rem & 1;
    if (set == 0) {
      CtxQ c = make_ctxQ<0>(spatial, ch);
      conv_accumQ<0>(xpad, wk, smem, c, acc);
#pragma unroll
      for (int i = 0; i < 2; ++i) {
        const int co = (ch * 8 + c.wv * 2 + i) * 16 + c.quad * 4;
        const float4 bs = *(const float4*)(bias1 + co);
        float m0 = 0.f, m1 = 0.f, m2 = 0.f, m3 = 0.f;
#pragma unroll
        for (int j = 0; j < 16; ++j) {             // j = h: in-lane max over h
          m0 = fmaxf(m0, acc[i][j][0] + bs.x);
          m1 = fmaxf(m1, acc[i][j][1] + bs.y);
          m2 = fmaxf(m2, acc[i][j][2] + bs.z);
          m3 = fmaxf(m3, acc[i][j][3] + bs.w);
        }
        unsigned* tgt = (unsigned*)(u_pad + ((size_t)c.b * 98 + (c.w0 + c.wl + 1)) * 256 + co);
        atomicMax(tgt + 0, __float_as_uint(m0));
        atomicMax(tgt + 1, __float_as_uint(m1));
        atomicMax(tgt + 2, __float_as_uint(m2));
        atomicMax(tgt + 3, __float_as_uint(m3));
      }
    } else {
      CtxQ c = make_ctxQ<1>(spatial, ch);
      conv_accumQ<1>(xpad, wk + WSET, smem, c, acc);
#pragma unroll
      for (int i = 0; i < 2; ++i) {
        const int co = (ch * 8 + c.wv * 2 + i) * 16 + c.quad * 4;
        const float4 bs = *(const float4*)(bias2 + co);
        float m0 = 0.f, m1 = 0.f, m2 = 0.f, m3 = 0.f;
#pragma unroll
        for (int j = 0; j < 16; ++j) {             // j = w: in-lane max over w
          m0 = fmaxf(m0, acc[i][j][0] + bs.x);
          m1 = fmaxf(m1, acc[i][j][1] + bs.y);
          m2 = fmaxf(m2, acc[i][j][2] + bs.z);
          m3 = fmaxf(m3, acc[i][j][3] + bs.w);
        }
        unsigned* tgt = (unsigned*)(v_pad + ((size_t)c.b * 98 + (c.h0 + c.wl + 1)) * 256 + co);
        atomicMax(tgt + 0, __float_as_uint(m0));
        atomicMax(tgt + 1, __float_as_uint(m1));
        atomicMax(tgt + 2, __float_as_uint(m2));
        atomicMax(tgt + 3, __float_as_uint(m3));
      }
    }
  } else {
    const int idx = lin - 1152;
    const int spatial = idx >> 1, ch = idx & 1;
    CtxQ c = make_ctxQ<0>(spatial, ch);
    conv_accumQ<0>(xpad, wk + (size_t)3 * WSET, smem, c, acc);
    const int w = c.w0 + c.wl;
#pragma unroll
    for (int i = 0; i < 2; ++i) {
      const int co = (ch * 8 + c.wv * 2 + i) * 16 + c.quad * 4;
      float4 bs = *(const float4*)(bias_p + co);
      const float4 b2 = *(const float4*)(bias_c1 + co);
      bs.x += b2.x; bs.y += b2.y; bs.z += b2.z; bs.w += b2.w;
#pragma unroll
      for (int j = 0; j < 16; ++j) {
        const int h = c.h0 + j;
        f16x4v pk;
        pk[0] = (_Float16)(acc[i][j][0] + bs.x);
        pk[1] = (_Float16)(acc[i][j][1] + bs.y);
        pk[2] = (_Float16)(acc[i][j][2] + bs.z);
        pk[3] = (_Float16)(acc[i][j][3] + bs.w);
        *(f16x4v*)(tmp + ((size_t)(c.b * 96 + h) * 96 + w) * 256 + co) = pk;
      }
    }
  }
}

// ---------------- 1D convs of u,v with case-summed weights ----------------
__global__ __launch_bounds__(256, 2) void k_uv1d(
    const float* __restrict__ u_pad, const float* __restrict__ v_pad,
    const _Float16* __restrict__ wuv, float* __restrict__ u2, float* __restrict__ v2)
{
  const int id = blockIdx.x;
  const int py = blockIdx.y;                     // 0..1 pos half
  const int b = id & 7, cs = (id >> 3) % 3, t = id / 24;
  const float* src = t ? v_pad : u_pad;
  float* dst = t ? v2 : u2;
  const _Float16* A0 = wuv + (size_t)(t * 3 + cs) * WUV_SET;
  const int lane = threadIdx.x & 63, wv = threadIdx.x >> 6;
  const int quad = lane >> 4, l16 = lane & 15;

  f32x4 acc[4][3];
#pragma unroll
  for (int i = 0; i < 4; ++i)
#pragma unroll
    for (int j = 0; j < 3; ++j) acc[i][j] = (f32x4){0.f, 0.f, 0.f, 0.f};

#pragma unroll 1
  for (int kb = 0; kb < 24; ++kb) {
    const int dw = kb >> 3, cb = kb & 7;
    f16x8 bf[3];
#pragma unroll
    for (int j = 0; j < 3; ++j) {
      const int pos = py * 48 + j * 16 + l16;
      const float* p = src + ((size_t)b * 98 + (pos + dw)) * 256 + cb * 32 + quad * 8;
      const float4 x0 = *(const float4*)p;
      const float4 x1 = *(const float4*)(p + 4);
      f16x8 v;
      v[0] = (_Float16)x0.x; v[1] = (_Float16)x0.y; v[2] = (_Float16)x0.z; v[3] = (_Float16)x0.w;
      v[4] = (_Float16)x1.x; v[5] = (_Float16)x1.y; v[6] = (_Float16)x1.z; v[7] = (_Float16)x1.w;
      bf[j] = v;
    }
    f16x8 af[4];
#pragma unroll
    for (int i = 0; i < 4; ++i)
      af[i] = *(const f16x8*)(A0 + (size_t)(kb * 16 + wv * 4 + i) * 512 + l16 * 32 + quad * 8);
#pragma unroll
    for (int i = 0; i < 4; ++i)
#pragma unroll
      for (int j = 0; j < 3; ++j)
        acc[i][j] = __builtin_amdgcn_mfma_f32_16x16x32_f16(af[i], bf[j], acc[i][j], 0, 0, 0);
  }
#pragma unroll
  for (int i = 0; i < 4; ++i)
#pragma unroll
    for (int j = 0; j < 3; ++j) {
      const int pos = py * 48 + j * 16 + l16;
      const int co = wv * 64 + i * 16 + quad * 4;
      *(f32x4*)(dst + ((size_t)(cs * 8 + b) * 96 + pos) * 256 + co) = acc[i][j];
    }
}

// ---------------- c1 epilogue: tmp + U' + V', relu -> r_pad NHWC f16 ------
__global__ __launch_bounds__(256, 8) void k_epi_c1(
    const _Float16* __restrict__ tmp,
    const float* __restrict__ u2, const float* __restrict__ v2,
    _Float16* __restrict__ rpad)
{
  const int gid = blockIdx.x;                    // 0..767
  const int b = gid / 96, h = gid - b * 96;
  const int hcase = (h == 0) ? 0 : ((h == 95) ? 2 : 1);
  const size_t tbase = (size_t)(b * 96 + h) * 96 * 256;
#pragma unroll 1
  for (int it = 0; it < 12; ++it) {
    const int chunk = it * 256 + threadIdx.x;    // 0..3071
    const int w = chunk >> 5;
    const int co8 = (chunk & 31) * 8;
    const int wcase = (w == 0) ? 0 : ((w == 95) ? 2 : 1);
    const f16x8 t = *(const f16x8*)(tmp + tbase + (size_t)w * 256 + co8);
    const float* up = u2 + ((size_t)(hcase * 8 + b) * 96 + w) * 256 + co8;
    const float* vp = v2 + ((size_t)(wcase * 8 + b) * 96 + h) * 256 + co8;
    const float4 u0 = *(const float4*)up, u1 = *(const float4*)(up + 4);
    const float4 v0 = *(const float4*)vp, v1 = *(const float4*)(vp + 4);
    f16x8 r;
    r[0] = (_Float16)fmaxf((float)t[0] + u0.x + v0.x, 0.f);
    r[1] = (_Float16)fmaxf((float)t[1] + u0.y + v0.y, 0.f);
    r[2] = (_Float16)fmaxf((float)t[2] + u0.z + v0.z, 0.f);
    r[3] = (_Float16)fmaxf((float)t[3] + u0.w + v0.w, 0.f);
    r[4] = (_Float16)fmaxf((float)t[4] + u1.x + v1.x, 0.f);
    r[5] = (_Float16)fmaxf((float)t[5] + u1.y + v1.y, 0.f);
    r[6] = (_Float16)fmaxf((float)t[6] + u1.z + v1.z, 0.f);
    r[7] = (_Float16)fmaxf((float)t[7] + u1.w + v1.w, 0.f);
    *(f16x8*)(rpad + ((size_t)(b * HP + h + 1) * WP + w + 1) * 256 + co8) = r;
  }
}

// ---------------- final conv, relu, NCHW f32 to d_out ---------------------
__global__ __launch_bounds__(128, 2) void k_conv_c2(
    const _Float16* __restrict__ rpad, const _Float16* __restrict__ wkc2,
    const float* __restrict__ bias, float* __restrict__ dout)
{
  __shared__ __align__(16) char smem[SMEM_Q];
  const int lin = xcd_swz(blockIdx.x, 1152);
  const int spatial = lin >> 2, ch = lin & 3;
  CtxB c = make_ctxB<0>(spatial, ch);
  f32x4 acc[2][16];
  ZERO_ACCQ(acc)
  conv_accumB<0>(rpad, wkc2, smem, c, acc);

  const int w = c.w0 + c.wl;
#pragma unroll
  for (int j = 0; j < 16; ++j) {
    const int h = c.h0 + j;
    float* op = dout + (size_t)c.b * 2359296 + h * 96 + w;
#pragma unroll
    for (int i = 0; i < 2; ++i) {
      const int co = (ch * 4 + c.wv * 2 + i) * 16 + c.quad * 4;
      const float4 bs = *(const float4*)(bias + co);
      op[(size_t)(co + 0) * 9216] = fmaxf(acc[i][j][0] + bs.x, 0.f);
      op[(size_t)(co + 1) * 9216] = fmaxf(acc[i][j][1] + bs.y, 0.f);
      op[(size_t)(co + 2) * 9216] = fmaxf(acc[i][j][2] + bs.z, 0.f);
      op[(size_t)(co + 3) * 9216] = fmaxf(acc[i][j][3] + bs.w, 0.f);
    }
  }
}

// ---------------- aux kernels ---------------------------------------------
// Zero the 1-px halo ring of x_pad (z=0) and r_pad (z=1). 388 border pos/img.
__global__ void k_border(_Float16* __restrict__ xpad, _Float16* __restrict__ rpad)
{
  const int idx = blockIdx.x, b = blockIdx.y;
  _Float16* buf = blockIdx.z ? rpad : xpad;
  int h, w;
  if (idx < 98)       { h = 0;  w = idx; }
  else if (idx < 196) { h = 97; w = idx - 98; }
  else { const int r = idx - 196; h = 1 + (r >> 1); w = (r & 1) ? 97 : 0; }
  buf[((size_t)(b * HP + h) * WP + w) * 256 + threadIdx.x] = (_Float16)0.f;
}

__global__ void k_pack_x(const float* __restrict__ x, _Float16* __restrict__ xpad)
{
  __shared__ float tile[32][33];
  const int bh = blockIdx.x;
  const int b = bh / 96, h = bh - b * 96;
  const int c0 = blockIdx.y * 32, w0 = blockIdx.z * 32;
  const int tx = threadIdx.x & 31, ty = threadIdx.x >> 5;
#pragma unroll
  for (int i = 0; i < 4; ++i) {
    int cI = c0 + ty + i * 8;
    tile[ty + i * 8][tx] = x[(((size_t)b * 256 + cI) * 96 + h) * 96 + w0 + tx];
  }
  __syncthreads();
#pragma unroll
  for (int i = 0; i < 4; ++i) {
    int w = w0 + ty + i * 8;
    xpad[((size_t)(b * HP + h + 1) * WP + (w + 1)) * 256 + c0 + tx] =
        (_Float16)tile[tx][ty + i * 8];
  }
}

// main conv weights -> tiled layout: idx = ((cb*9+tap)*16 + cog)*512 + m*32 + kk
__global__ void k_repack_w(const float* w0, const float* g0, const float* w1, const float* g1,
                           const float* w2, const float* g2, const float* w3, const float* g3,
                           const float* w4, const float* g4, _Float16* __restrict__ wk)
{
  const int set = blockIdx.y;
  const float* w; const float* g;
  switch (set) {
    case 0: w = w0; g = g0; break;
    case 1: w = w1; g = g1; break;
    case 2: w = w2; g = g2; break;
    case 3: w = w3; g = g3; break;
    default: w = w4; g = g4; break;
  }
  const int t = blockIdx.x * 256 + threadIdx.x;   // co*256 + ci
  const int co = t >> 8, ci = t & 255;
  const int cb = ci >> 5, kk = ci & 31, cog = co >> 4, m = co & 15;
  const float gv = g[co];
  const float* src = w + ((size_t)co * 256 + ci) * 9;
  _Float16* dst = wk + (size_t)set * WSET + cog * 512 + m * 32 + kk;
#pragma unroll
  for (int tap = 0; tap < 9; ++tap)
    dst[(cb * 9 + tap) * 8192] = (_Float16)(src[tap] * gv);
}

// case-summed 1D weights for U'/V'
__global__ void k_repack_uvw(const float* __restrict__ wp, const float* __restrict__ gp,
                             _Float16* __restrict__ wuv)
{
  const int tcs = blockIdx.y;                             // 0..5 = t*3+cs
  const int tt = tcs / 3, cs = tcs - tt * 3;
  const int idx = blockIdx.x * 256 + threadIdx.x;         // co*256 + ci
  const int co = idx >> 8, ci = idx & 255;
  const float gv = gp[co];
  const float* src = wp + ((size_t)co * 256 + ci) * 9;    // [dh][dw]
  const int lo = (cs == 0) ? 1 : 0, hi = (cs == 2) ? 1 : 2;
  _Float16* base = wuv + (size_t)tcs * WUV_SET;
#pragma unroll
  for (int d = 0; d < 3; ++d) {
    float s = 0.f;
    for (int e = lo; e <= hi; ++e)
      s += (tt == 0) ? src[e * 3 + d] : src[d * 3 + e];
    const int k = d * 256 + ci;
    const int kb = k >> 5, kk = k & 31;
    base[(size_t)(kb * 16 + (co >> 4)) * 512 + (co & 15) * 32 + kk] = (_Float16)(s * gv);
  }
}

// ---------------- launcher -------------------------------------------------
extern "C" void kernel_launch(void* const* d_in, const int* in_sizes, int n_in,
                              void* d_out, int out_size, void* d_ws, size_t ws_size,
                              hipStream_t stream)
{
  const float* x    = (const float*)d_in[0];
  const float* w_p1 = (const float*)d_in[1];
  const float* g_p1 = (const float*)d_in[2];
  const float* b_p1 = (const float*)d_in[3];
  const float* w_p2 = (const float*)d_in[4];
  const float* g_p2 = (const float*)d_in[5];
  const float* b_p2 = (const float*)d_in[6];
  const float* w_p  = (const float*)d_in[7];
  const float* g_p  = (const float*)d_in[8];
  const float* b_p  = (const float*)d_in[9];
  const float* w_c1 = (const float*)d_in[10];
  const float* g_c1 = (const float*)d_in[11];
  const float* b_c1 = (const float*)d_in[12];
  const float* w_c2 = (const float*)d_in[13];
  const float* g_c2 = (const float*)d_in[14];
  const float* b_c2 = (const float*)d_in[15];

  char* ws = (char*)d_ws;
  size_t off = 0;
  _Float16* x_pad = (_Float16*)(ws + off); off += XPAD_E * 2;
  _Float16* r_pad = (_Float16*)(ws + off); off += XPAD_E * 2;
  _Float16* wks   = (_Float16*)(ws + off); off += (size_t)5 * WSET * 2;
  _Float16* wuv   = (_Float16*)(ws + off); off += (size_t)6 * WUV_SET * 2;
  float*    u_pad = (float*)(ws + off);    off += UVP_E * 4;
  float*    v_pad = (float*)(ws + off);    off += UVP_E * 4;
  float*    u2    = (float*)(ws + off);    off += UV2_E * 4;
  float*    v2    = (float*)(ws + off);    off += UV2_E * 4;
  _Float16* tmp   = (_Float16*)d_out;      // c1 conv scratch; free until c2
  (void)ws_size; (void)in_sizes; (void)n_in; (void)out_size;

  hipMemsetAsync(u_pad, 0, UVP_E * 4, stream);     // atomicMax targets + zero pad
  hipMemsetAsync(v_pad, 0, UVP_E * 4, stream);

  k_border    <<<dim3(388, 8, 2), 256, 0, stream>>>(x_pad, r_pad);
  k_pack_x    <<<dim3(768, 8, 3), 256, 0, stream>>>(x, x_pad);
  k_repack_w  <<<dim3(256, 5),    256, 0, stream>>>(w_p1, g_p1, w_p2, g_p2, w_p, g_p,
                                                    w_c1, g_c1, w_c2, g_c2, wks);
  k_repack_uvw<<<dim3(256, 6),    256, 0, stream>>>(w_p, g_p, wuv);
  k_conv_main <<<1728, 256, 0, stream>>>(x_pad, wks, b_p1, b_p2, b_p, b_c1,
                                         u_pad, v_pad, tmp);
  k_uv1d      <<<dim3(48, 2), 256, 0, stream>>>(u_pad, v_pad, wuv, u2, v2);
  k_epi_c1    <<<768, 256, 0, stream>>>(tmp, u2, v2, r_pad);
  k_conv_c2   <<<1152, 128, 0, stream>>>(r_pad, wks + (size_t)4 * WSET, b_c2,
                                         (float*)d_out);
}